// Round 4
// baseline (1888.282 us; speedup 1.0000x reference)
//
#include <hip/hip_runtime.h>
#include <string.h>

typedef _Float16 f16x8 __attribute__((ext_vector_type(8)));
typedef _Float16 f16x4 __attribute__((ext_vector_type(4)));
typedef float    f32x4 __attribute__((ext_vector_type(4)));

// Generic 2-level row addressing: addr(r) = (r>>sh)*hi + (r&msk)*lo   (in elements)
struct Addr { long hi; long lo; int sh; int msk; };

__device__ __forceinline__ long raddr(const Addr a, int r) {
  return ((long)(r >> a.sh)) * a.hi + ((long)(r & a.msk)) * a.lo;
}

struct GP {
  int M, N, K1, K2;
  const float* A1; Addr a1;    // K-segment 1 rows
  const float* A2; Addr a2;    // K-segment 2 rows (optional, K2>0)
  const float* B;  int ldb;    // B[k][n], rows 0..K1+K2
  const float* scale;          // optional: alpha *= *scale
  float alpha;
  const float* E1; Addr e1; float beta;   // C1 = alpha*acc + beta*E1
  float* C1; Addr c1;
  float* C2; Addr c2;          // C2 = alpha*acc + E2
  const float* E2; Addr e2;
  const float* fin;            // 256 partials: stage-scale = 1/sqrt(sum)
  float* fout;                 // per-block sum of squares of written values
};

struct GPB { GP g[8]; };

// Tiled GEMM, f32 memory / f16 LDS / f32 accum. 4 waves (2x2), wave-tile BM/2 x BN/2.
// Single-buffer LDS (m93/m97 2-barrier structure). BK=32.
// A staged via f32x4 row loads; B staged via 4 column dword loads so the LDS
// write is a contiguous f16x4 along k (kills the 8-way transpose-write conflict).
// Requires (K1+K2) % 32 == 0, N % BN == 0.
template<int BM>
__device__ __forceinline__ void gemm_body(const GP& p) {
  constexpr int BN = BM;
  constexpr int WT = BM / 2;          // wave tile (square)
  constexpr int FM = WT / 16;         // fragments per wave dim (2 or 4)
  constexpr int NAQ = BM / 32;        // A f32x4 loads per thread
  constexpr int NBP = BN / 32;        // B column-load passes per thread
  constexpr int LNB = (BN == 64) ? 6 : 7;
  __shared__ _Float16 As[BM * 40];
  __shared__ _Float16 Bs[BN * 40];
  __shared__ float red[256];
  const int tid = threadIdx.x;
  const int nbn = (p.N + BN - 1) / BN;
  const int nbm = (p.M + BM - 1) / BM;
  if ((int)blockIdx.x >= nbm * nbn) return;
  int bm, bn;
  {
    const int bid = blockIdx.x;
    if ((nbm & 7) == 0) {   // stripe-XCD swizzle: all bn of a stripe -> same XCD
      bm = (bid & 7) + ((bid >> 3) / nbn) * 8;
      bn = (bid >> 3) % nbn;
    } else {
      bm = bid / nbn; bn = bid - bm * nbn;
    }
  }
  const int m0 = bm * BM, n0 = bn * BN;

  float sscale = 1.0f;
  if (p.fin) {
    red[tid] = p.fin[tid];
    __syncthreads();
    for (int st = 128; st > 0; st >>= 1) {
      if (tid < st) red[tid] += red[tid + st];
      __syncthreads();
    }
    sscale = 1.0f / sqrtf(red[0]);
    __syncthreads();
  }
  float alpha = p.alpha;
  if (p.scale) alpha *= p.scale[0];

  const int w = tid >> 6, l = tid & 63;
  const int wm = w >> 1, wn = w & 1;
  const int lr = l & 15, lg = l >> 4;
  const int bcol = tid & (BN - 1);          // B staging column
  const int bkg  = (tid >> LNB) * 4;        // B staging k base (0..)

  f32x4 acc[FM][FM];
  #pragma unroll
  for (int m = 0; m < FM; ++m)
    #pragma unroll
    for (int n = 0; n < FM; ++n) acc[m][n] = {0.f, 0.f, 0.f, 0.f};

  const int Kt = p.K1 + p.K2;

  for (int k0 = 0; k0 < Kt; k0 += 32) {
    const float* Ab; Addr aa; long kl;
    if (k0 < p.K1) { Ab = p.A1; aa = p.a1; kl = k0; }
    else           { Ab = p.A2; aa = p.a2; kl = (long)k0 - p.K1; }
    // ---- A stage: f32x4 row loads -> f16x4 writes at [row][kq*4] ----
    f32x4 aR[NAQ];
    #pragma unroll
    for (int i = 0; i < NAQ; ++i) {
      const int gq = tid + (i << 8);
      const int ar_ = gq >> 3, kq = gq & 7;
      f32x4 v = {0.f, 0.f, 0.f, 0.f};
      if (m0 + ar_ < p.M) v = *(const f32x4*)(Ab + raddr(aa, m0 + ar_) + kl + kq * 4);
      aR[i] = v;
    }
    // ---- B stage: 4 column dword loads -> f16x4 write at [n][k] ----
    float bR[NBP][4];
    #pragma unroll
    for (int ps = 0; ps < NBP; ++ps) {
      const int kk = bkg + ps * (1024 / BN);   // 16 for BN=64, 8 for BN=128
      #pragma unroll
      for (int j = 0; j < 4; ++j)
        bR[ps][j] = p.B[(long)(k0 + kk + j) * p.ldb + n0 + bcol];
    }
    #pragma unroll
    for (int i = 0; i < NAQ; ++i) {
      const int gq = tid + (i << 8);
      const int ar_ = gq >> 3, kq = gq & 7;
      f16x4 h;
      h[0] = (_Float16)(aR[i][0] * sscale);
      h[1] = (_Float16)(aR[i][1] * sscale);
      h[2] = (_Float16)(aR[i][2] * sscale);
      h[3] = (_Float16)(aR[i][3] * sscale);
      *(f16x4*)&As[ar_ * 40 + kq * 4] = h;
    }
    #pragma unroll
    for (int ps = 0; ps < NBP; ++ps) {
      const int kk = bkg + ps * (1024 / BN);
      f16x4 h;
      h[0] = (_Float16)(bR[ps][0] * sscale);
      h[1] = (_Float16)(bR[ps][1] * sscale);
      h[2] = (_Float16)(bR[ps][2] * sscale);
      h[3] = (_Float16)(bR[ps][3] * sscale);
      *(f16x4*)&Bs[bcol * 40 + kk] = h;
    }
    __syncthreads();
    f16x8 a[FM], b[FM];
    #pragma unroll
    for (int m = 0; m < FM; ++m)
      a[m] = *(const f16x8*)&As[(wm * WT + m * 16 + lr) * 40 + lg * 8];
    #pragma unroll
    for (int n = 0; n < FM; ++n)
      b[n] = *(const f16x8*)&Bs[(wn * WT + n * 16 + lr) * 40 + lg * 8];
    #pragma unroll
    for (int m = 0; m < FM; ++m)
      #pragma unroll
      for (int n = 0; n < FM; ++n)
        acc[m][n] = __builtin_amdgcn_mfma_f32_16x16x32_f16(a[m], b[n], acc[m][n], 0, 0, 0);
    __syncthreads();
  }

  float ssq = 0.0f;
  #pragma unroll
  for (int m = 0; m < FM; ++m) {
    #pragma unroll
    for (int n = 0; n < FM; ++n) {
      #pragma unroll
      for (int rr = 0; rr < 4; ++rr) {
        const int ro = m0 + wm * WT + m * 16 + lg * 4 + rr;
        const int no = n0 + wn * WT + n * 16 + lr;
        if (ro < p.M) {
          float val = alpha * acc[m][n][rr];
          if (p.C1) {
            float o1 = val;
            if (p.E1) o1 += p.beta * p.E1[raddr(p.e1, ro) + no];
            p.C1[raddr(p.c1, ro) + no] = o1;
          }
          if (p.C2) p.C2[raddr(p.c2, ro) + no] = val + p.E2[raddr(p.e2, ro) + no];
          ssq += val * val;
        }
      }
    }
  }
  if (p.fout) {
    __syncthreads();
    red[tid] = ssq;
    __syncthreads();
    for (int st = 128; st > 0; st >>= 1) {
      if (tid < st) red[tid] += red[tid + st];
      __syncthreads();
    }
    if (tid == 0) p.fout[blockIdx.x] = red[0];
  }
}

__global__ __launch_bounds__(256) void gemm_S(GPB pb) { gemm_body<64>(pb.g[blockIdx.y]); }
__global__ __launch_bounds__(256) void gemm_L(GPB pb) { gemm_body<128>(pb.g[blockIdx.y]); }

// out[i][j] = diag*(i==j) + sgn*mult*(*scale)*in[(roff+j)*ld + coff+i]
__global__ void tr_k(const float* in, long ld, long roff, long coff,
                     float* out, int n, const float* scale,
                     float mult, float diag, float sgn) {
  __shared__ float t[32][33];
  const int nb = n >> 5;
  const int bx = blockIdx.x % nb, by = blockIdx.x / nb;
  const long I0 = (long)bx * 32, J0 = (long)by * 32;
  const int tx = threadIdx.x, ty = threadIdx.y;
  #pragma unroll
  for (int k = 0; k < 4; ++k)
    t[ty * 4 + k][tx] = in[(roff + J0 + ty * 4 + k) * ld + coff + I0 + tx];
  __syncthreads();
  const float sc = scale ? scale[0] : 1.0f;
  const float f = sgn * mult * sc;
  #pragma unroll
  for (int k = 0; k < 4; ++k) {
    const long i = I0 + ty * 4 + k, j = J0 + tx;
    out[i * n + j] = ((i == j) ? diag : 0.0f) + f * t[tx][ty * 4 + k];
  }
}

__global__ void copy_rows_k(const float* src, Addr sa, float* dst, Addr da,
                            int M, int N4) {
  const long idx = (long)blockIdx.x * 256 + threadIdx.x;
  if (idx >= (long)M * N4) return;
  const int r = (int)(idx / N4);
  const long q = (idx - (long)r * N4) * 4;
  *(f32x4*)(dst + raddr(da, r) + q) = *(const f32x4*)(src + raddr(sa, r) + q);
}

// sigma from scale chain: ln l1(M0) = sum_{k<nsq} 2^-k ln s_k + 2^-nsq ln s_nsq
__global__ void scalar_k(const float* P, int nsq, const float* lg, float* sc) {
  __shared__ float red[256];
  __shared__ float sv[16];
  const int tid = threadIdx.x;
  for (int k = 0; k <= nsq; ++k) {
    red[tid] = P[k * 256 + tid];
    __syncthreads();
    for (int st = 128; st > 0; st >>= 1) {
      if (tid < st) red[tid] += red[tid + st];
      __syncthreads();
    }
    if (tid == 0) sv[k] = red[0];
    __syncthreads();
  }
  if (tid != 0) return;
  double lnl = 0.0, wgt = 1.0;
  for (int k = 0; k <= nsq; ++k) {
    double sk = sqrt((double)sv[k]);
    lnl += wgt * log(sk);
    if (k < nsq) wgt *= 0.5;
  }
  double sigma = exp(0.5 * lnl);
  if (sigma < 1e-5) sigma = 1e-5;
  const double invk = 1.0 / (sigma + 0.002);
  const double g = exp((double)lg[0]);
  sc[0] = (float)invk;        // invk
  sc[1] = (float)g;           // gamma
  sc[2] = (float)(g * invk);  // gamma*invk
}

static inline Addr lin(long stride) {
  Addr a; a.hi = 0; a.lo = stride; a.sh = 20; a.msk = 0xFFFFF; return a;
}
static inline Addr two(int sh, long hi, int msk, long lo) {
  Addr a; a.hi = hi; a.lo = lo; a.sh = sh; a.msk = msk; return a;
}
static inline GP gp0() {
  GP p; memset(&p, 0, sizeof(p)); p.alpha = 1.0f; p.beta = 1.0f; return p;
}

extern "C" void kernel_launch(void* const* d_in, const int* in_sizes, int n_in,
                              void* d_out, int out_size, void* d_ws, size_t ws_size,
                              hipStream_t stream) {
  (void)in_sizes; (void)n_in; (void)out_size; (void)ws_size;
  const float* u    = (const float*)d_in[0];  // [16][2048][512]
  const float* st0  = (const float*)d_in[1];  // [16][512]
  const float* S    = (const float*)d_in[2];  // [512][512]
  const float* Kr   = (const float*)d_in[3];  // [1024][1024]
  const float* lgam = (const float*)d_in[4];  // [1]

  float* outp   = (float*)d_out;                       // [16][2048][512]
  float* states = outp + (long)16 * 2048 * 512;        // [16][2049][512]
  float* ws = (float*)d_ws;

  const int NSQ = 12;
  float* sc = ws;                 // 3 scalars
  float* P  = ws + 64;            // (NSQ+1)*256 frobenius partials
  float* base = ws + 3456;

  // region1 (dead after scalar kernel)
  float* Krt = base;                  // 1024^2
  float* Ma  = base + 1048576;        // 1024^2
  float* Mb  = base + 2097152;        // 1024^2
  // region2 (overlaps region1; first written after scalar_k)
  float* St   = base;                 // 512^2 each below
  float* Xa   = base + 262144;
  float* Xb   = base + 524288;
  float* Yn   = base + 786432;
  float* K11t = base + 1048576;
  float* K12t = base + 1310720;
  float* K21t = base + 1572864;
  float* W    = base + 1835008;
  float* ABst = base + 2097152;       // [At;Bt] 1024x512
  float* CtDt = base + 2621440;       // [Ct;Dt] 1024x512  -> ends 3145728

  // big scratch lives in the outp region of d_out (dead before final GEMM writes)
  float* Za  = outp;                  // [16][512][512] Kogge-Stone ping
  float* Zb  = outp + 4194304;        // [16][512][512] Kogge-Stone pong
  float* APb = outp + 8388608;        // At^j, j=2..8 : APb+(j-2)*262144
  float* Tb  = outp + 10223616;       // Q^(2^k), k=1..8 : Tb+(k-1)*262144

  auto launchSb = [&](const GP* gs, int nb) {
    GPB pb; memset(&pb, 0, sizeof(pb));
    int mx = 0;
    for (int i = 0; i < nb; ++i) {
      pb.g[i] = gs[i];
      int b = ((gs[i].M + 63) / 64) * ((gs[i].N + 63) / 64);
      if (b > mx) mx = b;
    }
    gemm_S<<<dim3(mx, nb), dim3(256), 0, stream>>>(pb);
  };
  auto launchS = [&](const GP& g) { launchSb(&g, 1); };
  auto launchLb = [&](const GP* gs, int nb) {
    GPB pb; memset(&pb, 0, sizeof(pb));
    int mx = 0;
    for (int i = 0; i < nb; ++i) {
      pb.g[i] = gs[i];
      int b = ((gs[i].M + 127) / 128) * ((gs[i].N + 127) / 128);
      if (b > mx) mx = b;
    }
    gemm_L<<<dim3(mx, nb), dim3(256), 0, stream>>>(pb);
  };
  auto launchL = [&](const GP& g) { launchLb(&g, 1); };

  auto mm = [&](const float* A, const float* B, float* C) {
    GP g = gp0(); g.M = 512; g.N = 512; g.K1 = 512;
    g.A1 = A; g.a1 = lin(512); g.B = B; g.ldb = 512;
    g.C1 = C; g.c1 = lin(512);
    return g;
  };

  // ---- Phase A: sigma via squaring chain ----
  tr_k<<<dim3(1024), dim3(32, 8), 0, stream>>>(Kr, 1024, 0, 0, Krt, 1024,
                                               nullptr, 1.f, 0.f, 1.f);
  {
    GP g = gp0();
    g.M = 1024; g.N = 1024; g.K1 = 1024;
    g.A1 = Krt; g.a1 = lin(1024);
    g.B = Kr; g.ldb = 1024;
    g.C1 = Ma; g.c1 = lin(1024);
    g.fout = P;
    launchS(g);                // M0 = Kr^T Kr, partials P0
  }
  {
    float* cur = Ma; float* nxt = Mb;
    for (int k = 1; k <= NSQ; ++k) {
      GP g = gp0();
      g.M = 1024; g.N = 1024; g.K1 = 1024;
      g.A1 = cur; g.a1 = lin(1024);
      g.B = cur; g.ldb = 1024;
      g.C1 = nxt; g.c1 = lin(1024);
      g.fin = P + (long)(k - 1) * 256;
      g.fout = P + (long)k * 256;
      launchS(g);              // M_k = (M_{k-1}/s_{k-1})^2
      float* t = cur; cur = nxt; nxt = t;
    }
  }
  scalar_k<<<1, 256, 0, stream>>>(P, NSQ, lgam, sc);

  // ---- transposes / inits (region2 overwrites region1 from here) ----
  tr_k<<<dim3(256), dim3(32, 8), 0, stream>>>(S, 512, 0, 0, St, 512,
                                              nullptr, 1.f, 0.f, 1.f);     // St = S^T
  tr_k<<<dim3(256), dim3(32, 8), 0, stream>>>(S, 512, 0, 0, Xa, 512,
                                              nullptr, 1.f, 2.f, -1.f);    // X0 = 2I - S^T
  tr_k<<<dim3(256), dim3(32, 8), 0, stream>>>(Kr, 1024, 0, 0, K11t, 512,
                                              sc, 1.f, 0.f, 1.f);          // K11^T * invk
  tr_k<<<dim3(256), dim3(32, 8), 0, stream>>>(Kr, 1024, 0, 512, K12t, 512,
                                              sc, 1.f, 0.f, 1.f);          // K12^T * invk
  tr_k<<<dim3(256), dim3(32, 8), 0, stream>>>(Kr, 1024, 512, 0, K21t, 512,
                                              sc, 1.f, 0.f, 1.f);          // K21^T * invk
  tr_k<<<dim3(256), dim3(32, 8), 0, stream>>>(Kr, 1024, 512, 512, CtDt + 262144,
                                              512, sc + 2, 1.f, 0.f, 1.f); // Dt = g*invk*K22^T

  // ---- Newton: SinvT = (S^T)^-1, 3 iterations -> Xb ----
  for (int k = 0; k < 3; ++k) {
    float* cur = (k % 2 == 0) ? Xa : Xb;
    float* nxt = (k % 2 == 0) ? Xb : Xa;
    GP g = gp0();
    g.M = 512; g.N = 512; g.K1 = 512;
    g.A1 = St; g.a1 = lin(512);
    g.B = cur; g.ldb = 512;
    g.C1 = Yn; g.c1 = lin(512);
    launchS(g);                // Yn = St @ X
    GP h = gp0();
    h.M = 512; h.N = 512; h.K1 = 512;
    h.A1 = cur; h.a1 = lin(512);
    h.B = Yn; h.ldb = 512;
    h.alpha = -1.0f;
    h.E1 = cur; h.e1 = lin(512); h.beta = 2.0f;
    h.C1 = nxt; h.c1 = lin(512);
    launchS(h);                // X' = 2X - X@Yn
  }
  float* SinvT = Xb;

  // ---- {W, Ct} then {At, Bt} ----
  {
    GP gs[2];
    gs[0] = mm(K11t, SinvT, W);                       // W = K11t @ SinvT
    gs[1] = mm(St, K21t, CtDt);                       // Ct = St @ K21t
    launchSb(gs, 2);
  }
  {
    GP gs[2];
    gs[0] = mm(St, W, ABst);                          // At = St @ W
    gs[1] = mm(K12t, SinvT, ABst + 262144);           // Bt = gamma*K12t@SinvT
    gs[1].scale = sc + 1;
    launchSb(gs, 2);
  }

  // ---- At powers j=2..8 via doubling (AP(1) aliases ABst) ----
  auto AP = [&](int j) -> float* {
    return (j == 1) ? ABst : APb + (long)(j - 2) * 262144;
  };
  { GP g = mm(AP(1), AP(1), AP(2)); launchS(g); }
  { GP gs[2] = { mm(AP(2), AP(1), AP(3)), mm(AP(2), AP(2), AP(4)) };
    launchSb(gs, 2); }
  { GP gs[4]; for (int i = 1; i <= 4; ++i) gs[i-1] = mm(AP(4), AP(i), AP(4+i));
    launchSb(gs, 4); }

  // ---- T(k) = Q^(2^k), Q = At^8 ; T(0)=AP(8), T(k)=T(k-1)^2 ----
  auto Tm = [&](int k) -> float* {
    return (k == 0) ? AP(8) : Tb + (long)(k - 1) * 262144;
  };
  for (int k = 1; k <= 8; ++k) { GP g = mm(Tm(k-1), Tm(k-1), Tm(k)); launchS(g); }

  // Addressing constants (L=8, 256 chunks/batch)
  const Addr A_u8   = two(8, 1048576, 255, 4096);   // u[b][8c] rows, r=(b<<8)|c
  const Addr A_s8   = two(8, 1049088, 255, 4096);   // states[b][8c] rows
  const Addr A_z    = two(8, 262144, 255, 512);     // Z[b][c] slots (512-slot pad)
  const Addr A_srow = two(11, 1049088, 2047, 512);  // states[b][t]

  // Z init: slot (b,0) = initial state; pass1 j=8 fills slots 1..256
  copy_rows_k<<<dim3(8), dim3(256), 0, stream>>>(st0, lin(512), Za, lin(262144),
                                                 16, 128);

  // ---- pass1: local zero-init scans; l_j -> states slot c*8+j (j=1..7), l_8 -> Za[c+1]
  for (int j = 1; j <= 8; ++j) {
    GP g = gp0();
    g.M = 4096; g.N = 512; g.ldb = 512;
    if (j == 1) {
      g.K1 = 512; g.A1 = u; g.a1 = A_u8;
      g.B = ABst + 262144;   // Bt only
    } else {
      g.K1 = 512; g.A1 = states + (long)(j - 1) * 512; g.a1 = A_s8;
      g.K2 = 512; g.A2 = u + (long)(j - 1) * 512; g.a2 = A_u8;
      g.B = ABst;            // [At; Bt]
    }
    if (j == 8) { g.C1 = Za + 512; g.c1 = A_z; }
    else { g.C1 = states + (long)j * 512; g.c1 = A_s8; }
    launchS(g);
  }

  // ---- Kogge-Stone weighted prefix over 257 chunk states ----
  // W_c <- W_c + W_{c-2^k} @ Q^(2^k), k=0..8; ping-pong Za/Zb (512-slot padded)
  for (int k = 0; k <= 8; ++k) {
    const int s = 1 << k;
    float* Zs = (k % 2 == 0) ? Za : Zb;
    float* Zd = (k % 2 == 0) ? Zb : Za;
    GP g = gp0();
    g.M = 4096; g.N = 512; g.K1 = 512;
    g.A1 = Zs; g.a1 = A_z;                       // W_{c-s}, rows (b, i=c-s)
    g.B = Tm(k); g.ldb = 512;
    g.E1 = Zs + (long)s * 512; g.e1 = A_z; g.beta = 1.0f;
    g.C1 = Zd + (long)s * 512; g.c1 = A_z;
    launchS(g);
    // carry over untouched slots c < s
    copy_rows_k<<<dim3(8 * s), dim3(256), 0, stream>>>(
        Zs, two(k, 262144, s - 1, 512), Zd, two(k, 262144, s - 1, 512),
        16 * s, 128);
  }
  float* Zf = Zb;   // 9 rounds: Za->Zb->...->Zb

  // states[b][c*8] = Zf[b][c];  states[b][2048] = Zf[b][256]
  copy_rows_k<<<dim3(2048), dim3(256), 0, stream>>>(Zf, A_z, states, A_s8,
                                                    4096, 128);
  copy_rows_k<<<dim3(8), dim3(256), 0, stream>>>(Zf + (long)256 * 512, lin(262144),
                                                 states + (long)2048 * 512,
                                                 lin(1049088), 16, 128);

  // ---- corrections (batched): states[b][c*8+j] += Zf[b][c] @ At^j, j=1..7 ----
  {
    GP gs[7];
    for (int j = 1; j <= 7; ++j) {
      GP g = gp0();
      g.M = 4096; g.N = 512; g.K1 = 512;
      g.A1 = Zf; g.a1 = A_z;
      g.B = AP(j); g.ldb = 512;
      g.C2 = states + (long)j * 512; g.c2 = A_s8;
      g.E2 = states + (long)j * 512; g.e2 = A_s8;
      gs[j - 1] = g;
    }
    launchLb(gs, 7);
  }

  // ---- output = states[:, :T] @ Ct + u @ Dt ----
  {
    GP g = gp0();
    g.M = 32768; g.N = 512;
    g.K1 = 512; g.A1 = states; g.a1 = A_srow;
    g.K2 = 512; g.A2 = u; g.a2 = lin(512);
    g.B = CtDt; g.ldb = 512;
    g.C1 = outp; g.c1 = lin(512);
    launchL(g);
  }
}

// Round 5
// 1543.748 us; speedup vs baseline: 1.2232x; 1.2232x over previous
//
#include <hip/hip_runtime.h>
#include <string.h>

typedef _Float16 f16x8 __attribute__((ext_vector_type(8)));
typedef _Float16 f16x4 __attribute__((ext_vector_type(4)));
typedef float    f32x4 __attribute__((ext_vector_type(4)));

// Generic 2-level row addressing: addr(r) = (r>>sh)*hi + (r&msk)*lo   (in elements)
struct Addr { long hi; long lo; int sh; int msk; };

__device__ __forceinline__ long raddr(const Addr a, int r) {
  return ((long)(r >> a.sh)) * a.hi + ((long)(r & a.msk)) * a.lo;
}

struct GP {
  int M, N, K1, K2;
  const float* A1; Addr a1;    // K-segment 1 rows
  const float* A2; Addr a2;    // K-segment 2 rows (optional, K2>0)
  const float* B;  int ldb;    // B[k][n], rows 0..K1+K2
  const float* scale;          // optional: alpha *= *scale
  float alpha;
  const float* E1; Addr e1; float beta;   // C1 = alpha*acc + beta*E1
  float* C1; Addr c1;
  float* C2; Addr c2;          // C2 = alpha*acc + E2
  const float* E2; Addr e2;
  const float* fin;            // 256 partials: stage-scale = 1/sqrt(sum)
  float* fout;                 // per-block sum of squares of written values
};

struct GPB { GP g[8]; };

// Tiled GEMM, f32 memory / f16 LDS / f32 accum. 4 waves (2x2), wave-tile BM/2 x BN/2.
// Single LDS buffer, m97 2-barrier structure WITH register prefetch: next tile's
// global loads issue before the current tile's compute, hiding VMEM latency.
// B staged via 4 column dword loads -> contiguous f16x4 LDS write along k
// (conflict-free; round-3's transpose-write was an 8-way conflict).
// Requires (K1+K2) % 64 == 0, N % BN == 0.
template<int BM>
__device__ __forceinline__ void gemm_body(const GP& p) {
  constexpr int BN = BM;
  constexpr int WT = BM / 2;          // wave tile (square)
  constexpr int FM = WT / 16;         // fragments per wave dim (2 or 4)
  constexpr int NAQ = BM / 32;        // A f32x4 loads per thread
  constexpr int NBP = BN / 32;        // B column-load passes per thread
  constexpr int LNB = (BN == 64) ? 6 : 7;
  __shared__ _Float16 As[BM * 40];
  __shared__ _Float16 Bs[BN * 40];
  __shared__ float red[256];
  const int tid = threadIdx.x;
  const int nbn = (p.N + BN - 1) / BN;
  const int nbm = (p.M + BM - 1) / BM;
  if ((int)blockIdx.x >= nbm * nbn) return;
  int bm, bn;
  {
    const int bid = blockIdx.x;
    if ((nbm & 7) == 0) {   // stripe-XCD swizzle: all bn of a stripe -> same XCD
      bm = (bid & 7) + ((bid >> 3) / nbn) * 8;
      bn = (bid >> 3) % nbn;
    } else {
      bm = bid / nbn; bn = bid - bm * nbn;
    }
  }
  const int m0 = bm * BM, n0 = bn * BN;

  float sscale = 1.0f;
  if (p.fin) {
    red[tid] = p.fin[tid];
    __syncthreads();
    for (int st = 128; st > 0; st >>= 1) {
      if (tid < st) red[tid] += red[tid + st];
      __syncthreads();
    }
    sscale = 1.0f / sqrtf(red[0]);
    __syncthreads();
  }
  float alpha = p.alpha;
  if (p.scale) alpha *= p.scale[0];

  const int w = tid >> 6, l = tid & 63;
  const int wm = w >> 1, wn = w & 1;
  const int lr = l & 15, lg = l >> 4;
  const int bcol = tid & (BN - 1);          // B staging column
  const int bkg  = (tid >> LNB) * 4;        // B staging k base

  f32x4 acc[FM][FM];
  #pragma unroll
  for (int m = 0; m < FM; ++m)
    #pragma unroll
    for (int n = 0; n < FM; ++n) acc[m][n] = {0.f, 0.f, 0.f, 0.f};

  const int Kt = p.K1 + p.K2;

  f32x4 aR0[NAQ], aR1[NAQ];
  float bR0[NBP][4], bR1[NBP][4];

  auto loadT = [&](int k0, f32x4* aR, float (*bR)[4]) {
    const float* Ab; Addr aa; long kl;
    if (k0 < p.K1) { Ab = p.A1; aa = p.a1; kl = k0; }
    else           { Ab = p.A2; aa = p.a2; kl = (long)k0 - p.K1; }
    #pragma unroll
    for (int i = 0; i < NAQ; ++i) {
      const int gq = tid + (i << 8);
      const int ar_ = gq >> 3, kq = gq & 7;
      f32x4 v = {0.f, 0.f, 0.f, 0.f};
      if (m0 + ar_ < p.M) v = *(const f32x4*)(Ab + raddr(aa, m0 + ar_) + kl + kq * 4);
      aR[i] = v;
    }
    #pragma unroll
    for (int ps = 0; ps < NBP; ++ps) {
      const int kk = bkg + ps * (1024 / BN);
      #pragma unroll
      for (int j = 0; j < 4; ++j)
        bR[ps][j] = p.B[(long)(k0 + kk + j) * p.ldb + n0 + bcol];
    }
  };
  auto storeLDS = [&](const f32x4* aR, const float (*bR)[4]) {
    #pragma unroll
    for (int i = 0; i < NAQ; ++i) {
      const int gq = tid + (i << 8);
      const int ar_ = gq >> 3, kq = gq & 7;
      f16x4 h;
      h[0] = (_Float16)(aR[i][0] * sscale);
      h[1] = (_Float16)(aR[i][1] * sscale);
      h[2] = (_Float16)(aR[i][2] * sscale);
      h[3] = (_Float16)(aR[i][3] * sscale);
      *(f16x4*)&As[ar_ * 40 + kq * 4] = h;
    }
    #pragma unroll
    for (int ps = 0; ps < NBP; ++ps) {
      const int kk = bkg + ps * (1024 / BN);
      f16x4 h;
      h[0] = (_Float16)(bR[ps][0] * sscale);
      h[1] = (_Float16)(bR[ps][1] * sscale);
      h[2] = (_Float16)(bR[ps][2] * sscale);
      h[3] = (_Float16)(bR[ps][3] * sscale);
      *(f16x4*)&Bs[bcol * 40 + kk] = h;
    }
  };
  auto compute = [&]() {
    f16x8 a[FM], b[FM];
    #pragma unroll
    for (int m = 0; m < FM; ++m)
      a[m] = *(const f16x8*)&As[(wm * WT + m * 16 + lr) * 40 + lg * 8];
    #pragma unroll
    for (int n = 0; n < FM; ++n)
      b[n] = *(const f16x8*)&Bs[(wn * WT + n * 16 + lr) * 40 + lg * 8];
    #pragma unroll
    for (int m = 0; m < FM; ++m)
      #pragma unroll
      for (int n = 0; n < FM; ++n)
        acc[m][n] = __builtin_amdgcn_mfma_f32_16x16x32_f16(a[m], b[n], acc[m][n], 0, 0, 0);
  };

  loadT(0, aR0, bR0);
  for (int k0 = 0; k0 < Kt; k0 += 64) {
    storeLDS(aR0, bR0);
    __syncthreads();
    loadT(k0 + 32, aR1, bR1);       // prefetch: VMEM overlaps compute below
    compute();
    __syncthreads();
    storeLDS(aR1, bR1);
    __syncthreads();
    if (k0 + 64 < Kt) loadT(k0 + 64, aR0, bR0);
    compute();
    __syncthreads();
  }

  float ssq = 0.0f;
  #pragma unroll
  for (int m = 0; m < FM; ++m) {
    #pragma unroll
    for (int n = 0; n < FM; ++n) {
      #pragma unroll
      for (int rr = 0; rr < 4; ++rr) {
        const int ro = m0 + wm * WT + m * 16 + lg * 4 + rr;
        const int no = n0 + wn * WT + n * 16 + lr;
        if (ro < p.M) {
          float val = alpha * acc[m][n][rr];
          if (p.C1) {
            float o1 = val;
            if (p.E1) o1 += p.beta * p.E1[raddr(p.e1, ro) + no];
            p.C1[raddr(p.c1, ro) + no] = o1;
          }
          if (p.C2) p.C2[raddr(p.c2, ro) + no] = val + p.E2[raddr(p.e2, ro) + no];
          ssq += val * val;
        }
      }
    }
  }
  if (p.fout) {
    __syncthreads();
    red[tid] = ssq;
    __syncthreads();
    for (int st = 128; st > 0; st >>= 1) {
      if (tid < st) red[tid] += red[tid + st];
      __syncthreads();
    }
    if (tid == 0) p.fout[blockIdx.x] = red[0];
  }
}

__global__ __launch_bounds__(256) void gemm_S(GPB pb) { gemm_body<64>(pb.g[blockIdx.y]); }
__global__ __launch_bounds__(256) void gemm_L(GPB pb) { gemm_body<128>(pb.g[blockIdx.y]); }

// out[i][j] = diag*(i==j) + sgn*mult*(*scale)*in[(roff+j)*ld + coff+i]
__global__ void tr_k(const float* in, long ld, long roff, long coff,
                     float* out, int n, const float* scale,
                     float mult, float diag, float sgn) {
  __shared__ float t[32][33];
  const int nb = n >> 5;
  const int bx = blockIdx.x % nb, by = blockIdx.x / nb;
  const long I0 = (long)bx * 32, J0 = (long)by * 32;
  const int tx = threadIdx.x, ty = threadIdx.y;
  #pragma unroll
  for (int k = 0; k < 4; ++k)
    t[ty * 4 + k][tx] = in[(roff + J0 + ty * 4 + k) * ld + coff + I0 + tx];
  __syncthreads();
  const float sc = scale ? scale[0] : 1.0f;
  const float f = sgn * mult * sc;
  #pragma unroll
  for (int k = 0; k < 4; ++k) {
    const long i = I0 + ty * 4 + k, j = J0 + tx;
    out[i * n + j] = ((i == j) ? diag : 0.0f) + f * t[tx][ty * 4 + k];
  }
}

__global__ void copy_rows_k(const float* src, Addr sa, float* dst, Addr da,
                            int M, int N4) {
  const long idx = (long)blockIdx.x * 256 + threadIdx.x;
  if (idx >= (long)M * N4) return;
  const int r = (int)(idx / N4);
  const long q = (idx - (long)r * N4) * 4;
  *(f32x4*)(dst + raddr(da, r) + q) = *(const f32x4*)(src + raddr(sa, r) + q);
}

// sigma from scale chain: ln l1(M0) = sum_{k<nsq} 2^-k ln s_k + 2^-nsq ln s_nsq
__global__ void scalar_k(const float* P, int nsq, const float* lg, float* sc) {
  __shared__ float red[256];
  __shared__ float sv[16];
  const int tid = threadIdx.x;
  for (int k = 0; k <= nsq; ++k) {
    red[tid] = P[k * 256 + tid];
    __syncthreads();
    for (int st = 128; st > 0; st >>= 1) {
      if (tid < st) red[tid] += red[tid + st];
      __syncthreads();
    }
    if (tid == 0) sv[k] = red[0];
    __syncthreads();
  }
  if (tid != 0) return;
  double lnl = 0.0, wgt = 1.0;
  for (int k = 0; k <= nsq; ++k) {
    double sk = sqrt((double)sv[k]);
    lnl += wgt * log(sk);
    if (k < nsq) wgt *= 0.5;
  }
  double sigma = exp(0.5 * lnl);
  if (sigma < 1e-5) sigma = 1e-5;
  const double invk = 1.0 / (sigma + 0.002);
  const double g = exp((double)lg[0]);
  sc[0] = (float)invk;        // invk
  sc[1] = (float)g;           // gamma
  sc[2] = (float)(g * invk);  // gamma*invk
}

static inline Addr lin(long stride) {
  Addr a; a.hi = 0; a.lo = stride; a.sh = 20; a.msk = 0xFFFFF; return a;
}
static inline Addr two(int sh, long hi, int msk, long lo) {
  Addr a; a.hi = hi; a.lo = lo; a.sh = sh; a.msk = msk; return a;
}
static inline GP gp0() {
  GP p; memset(&p, 0, sizeof(p)); p.alpha = 1.0f; p.beta = 1.0f; return p;
}

extern "C" void kernel_launch(void* const* d_in, const int* in_sizes, int n_in,
                              void* d_out, int out_size, void* d_ws, size_t ws_size,
                              hipStream_t stream) {
  (void)in_sizes; (void)n_in; (void)out_size; (void)ws_size;
  const float* u    = (const float*)d_in[0];  // [16][2048][512]
  const float* st0  = (const float*)d_in[1];  // [16][512]
  const float* S    = (const float*)d_in[2];  // [512][512]
  const float* Kr   = (const float*)d_in[3];  // [1024][1024]
  const float* lgam = (const float*)d_in[4];  // [1]

  float* outp   = (float*)d_out;                       // [16][2048][512]
  float* states = outp + (long)16 * 2048 * 512;        // [16][2049][512]
  float* ws = (float*)d_ws;

  const int NSQ = 12;
  float* sc = ws;                 // 3 scalars
  float* P  = ws + 64;            // (NSQ+1)*256 frobenius partials
  float* base = ws + 3456;

  // region1 (dead after scalar kernel)
  float* Krt = base;                  // 1024^2
  float* Ma  = base + 1048576;        // 1024^2
  float* Mb  = base + 2097152;        // 1024^2
  // region2 (overlaps region1; first written after scalar_k)
  float* St   = base;                 // 512^2 each below
  float* Xa   = base + 262144;
  float* Xb   = base + 524288;
  float* Yn   = base + 786432;
  float* K11t = base + 1048576;
  float* K12t = base + 1310720;
  float* K21t = base + 1572864;
  float* W    = base + 1835008;
  float* ABst = base + 2097152;       // [At;Bt] 1024x512
  float* CtDt = base + 2621440;       // [Ct;Dt] 1024x512  -> ends 3145728

  // big scratch lives in the outp region of d_out (dead before final GEMM writes)
  float* Za  = outp;                  // [16][512][512] Kogge-Stone ping
  float* Zb  = outp + 4194304;        // [16][512][512] Kogge-Stone pong
  float* APb = outp + 8388608;        // At^j, j=2..8 : APb+(j-2)*262144
  float* Tb  = outp + 10223616;       // Q^(2^k), k=1..8 : Tb+(k-1)*262144

  auto launchSb = [&](const GP* gs, int nb) {
    GPB pb; memset(&pb, 0, sizeof(pb));
    int mx = 0;
    for (int i = 0; i < nb; ++i) {
      pb.g[i] = gs[i];
      int b = ((gs[i].M + 63) / 64) * ((gs[i].N + 63) / 64);
      if (b > mx) mx = b;
    }
    gemm_S<<<dim3(mx, nb), dim3(256), 0, stream>>>(pb);
  };
  auto launchS = [&](const GP& g) { launchSb(&g, 1); };
  auto launchLb = [&](const GP* gs, int nb) {
    GPB pb; memset(&pb, 0, sizeof(pb));
    int mx = 0;
    for (int i = 0; i < nb; ++i) {
      pb.g[i] = gs[i];
      int b = ((gs[i].M + 127) / 128) * ((gs[i].N + 127) / 128);
      if (b > mx) mx = b;
    }
    gemm_L<<<dim3(mx, nb), dim3(256), 0, stream>>>(pb);
  };
  auto launchL = [&](const GP& g) { launchLb(&g, 1); };

  auto mm = [&](const float* A, const float* B, float* C) {
    GP g = gp0(); g.M = 512; g.N = 512; g.K1 = 512;
    g.A1 = A; g.a1 = lin(512); g.B = B; g.ldb = 512;
    g.C1 = C; g.c1 = lin(512);
    return g;
  };

  // ---- Phase A: sigma via squaring chain ----
  tr_k<<<dim3(1024), dim3(32, 8), 0, stream>>>(Kr, 1024, 0, 0, Krt, 1024,
                                               nullptr, 1.f, 0.f, 1.f);
  {
    GP g = gp0();
    g.M = 1024; g.N = 1024; g.K1 = 1024;
    g.A1 = Krt; g.a1 = lin(1024);
    g.B = Kr; g.ldb = 1024;
    g.C1 = Ma; g.c1 = lin(1024);
    g.fout = P;
    launchS(g);                // M0 = Kr^T Kr, partials P0
  }
  {
    float* cur = Ma; float* nxt = Mb;
    for (int k = 1; k <= NSQ; ++k) {
      GP g = gp0();
      g.M = 1024; g.N = 1024; g.K1 = 1024;
      g.A1 = cur; g.a1 = lin(1024);
      g.B = cur; g.ldb = 1024;
      g.C1 = nxt; g.c1 = lin(1024);
      g.fin = P + (long)(k - 1) * 256;
      g.fout = P + (long)k * 256;
      launchS(g);              // M_k = (M_{k-1}/s_{k-1})^2
      float* t = cur; cur = nxt; nxt = t;
    }
  }
  scalar_k<<<1, 256, 0, stream>>>(P, NSQ, lgam, sc);

  // ---- transposes / inits (region2 overwrites region1 from here) ----
  tr_k<<<dim3(256), dim3(32, 8), 0, stream>>>(S, 512, 0, 0, St, 512,
                                              nullptr, 1.f, 0.f, 1.f);     // St = S^T
  tr_k<<<dim3(256), dim3(32, 8), 0, stream>>>(S, 512, 0, 0, Xa, 512,
                                              nullptr, 1.f, 2.f, -1.f);    // X0 = 2I - S^T
  tr_k<<<dim3(256), dim3(32, 8), 0, stream>>>(Kr, 1024, 0, 0, K11t, 512,
                                              sc, 1.f, 0.f, 1.f);          // K11^T * invk
  tr_k<<<dim3(256), dim3(32, 8), 0, stream>>>(Kr, 1024, 0, 512, K12t, 512,
                                              sc, 1.f, 0.f, 1.f);          // K12^T * invk
  tr_k<<<dim3(256), dim3(32, 8), 0, stream>>>(Kr, 1024, 512, 0, K21t, 512,
                                              sc, 1.f, 0.f, 1.f);          // K21^T * invk
  tr_k<<<dim3(256), dim3(32, 8), 0, stream>>>(Kr, 1024, 512, 512, CtDt + 262144,
                                              512, sc + 2, 1.f, 0.f, 1.f); // Dt = g*invk*K22^T

  // ---- Newton: SinvT = (S^T)^-1, 3 iterations -> Xb ----
  for (int k = 0; k < 3; ++k) {
    float* cur = (k % 2 == 0) ? Xa : Xb;
    float* nxt = (k % 2 == 0) ? Xb : Xa;
    GP g = gp0();
    g.M = 512; g.N = 512; g.K1 = 512;
    g.A1 = St; g.a1 = lin(512);
    g.B = cur; g.ldb = 512;
    g.C1 = Yn; g.c1 = lin(512);
    launchS(g);                // Yn = St @ X
    GP h = gp0();
    h.M = 512; h.N = 512; h.K1 = 512;
    h.A1 = cur; h.a1 = lin(512);
    h.B = Yn; h.ldb = 512;
    h.alpha = -1.0f;
    h.E1 = cur; h.e1 = lin(512); h.beta = 2.0f;
    h.C1 = nxt; h.c1 = lin(512);
    launchS(h);                // X' = 2X - X@Yn
  }
  float* SinvT = Xb;

  // ---- {W, Ct} then {At, Bt} ----
  {
    GP gs[2];
    gs[0] = mm(K11t, SinvT, W);                       // W = K11t @ SinvT
    gs[1] = mm(St, K21t, CtDt);                       // Ct = St @ K21t
    launchSb(gs, 2);
  }
  {
    GP gs[2];
    gs[0] = mm(St, W, ABst);                          // At = St @ W
    gs[1] = mm(K12t, SinvT, ABst + 262144);           // Bt = gamma*K12t@SinvT
    gs[1].scale = sc + 1;
    launchSb(gs, 2);
  }

  // ---- At powers j=2..8 via doubling (AP(1) aliases ABst) ----
  auto AP = [&](int j) -> float* {
    return (j == 1) ? ABst : APb + (long)(j - 2) * 262144;
  };
  { GP g = mm(AP(1), AP(1), AP(2)); launchS(g); }
  { GP gs[2] = { mm(AP(2), AP(1), AP(3)), mm(AP(2), AP(2), AP(4)) };
    launchSb(gs, 2); }
  { GP gs[4]; for (int i = 1; i <= 4; ++i) gs[i-1] = mm(AP(4), AP(i), AP(4+i));
    launchSb(gs, 4); }

  // ---- T(k) = Q^(2^k), Q = At^8 ; T(0)=AP(8), T(k)=T(k-1)^2 ----
  auto Tm = [&](int k) -> float* {
    return (k == 0) ? AP(8) : Tb + (long)(k - 1) * 262144;
  };
  for (int k = 1; k <= 8; ++k) { GP g = mm(Tm(k-1), Tm(k-1), Tm(k)); launchS(g); }

  // Addressing constants (L=8, 256 chunks/batch)
  const Addr A_u8   = two(8, 1048576, 255, 4096);   // u[b][8c] rows, r=(b<<8)|c
  const Addr A_s8   = two(8, 1049088, 255, 4096);   // states[b][8c] rows
  const Addr A_z    = two(8, 262144, 255, 512);     // Z[b][c] slots (512-slot pad)
  const Addr A_srow = two(11, 1049088, 2047, 512);  // states[b][t]

  // Z init: slot (b,0) = initial state; pass1 j=8 fills slots 1..256
  copy_rows_k<<<dim3(8), dim3(256), 0, stream>>>(st0, lin(512), Za, lin(262144),
                                                 16, 128);

  // ---- pass1: local zero-init scans; l_j -> states slot c*8+j (j=1..7), l_8 -> Za[c+1]
  for (int j = 1; j <= 8; ++j) {
    GP g = gp0();
    g.M = 4096; g.N = 512; g.ldb = 512;
    if (j == 1) {
      g.K1 = 512; g.A1 = u; g.a1 = A_u8;
      g.B = ABst + 262144;   // Bt only
    } else {
      g.K1 = 512; g.A1 = states + (long)(j - 1) * 512; g.a1 = A_s8;
      g.K2 = 512; g.A2 = u + (long)(j - 1) * 512; g.a2 = A_u8;
      g.B = ABst;            // [At; Bt]
    }
    if (j == 8) { g.C1 = Za + 512; g.c1 = A_z; }
    else { g.C1 = states + (long)j * 512; g.c1 = A_s8; }
    launchS(g);
  }

  // ---- Kogge-Stone weighted prefix over 257 chunk states ----
  // W_c <- W_c + W_{c-2^k} @ Q^(2^k), k=0..8; ping-pong Za/Zb (512-slot padded)
  for (int k = 0; k <= 8; ++k) {
    const int s = 1 << k;
    float* Zs = (k % 2 == 0) ? Za : Zb;
    float* Zd = (k % 2 == 0) ? Zb : Za;
    GP g = gp0();
    g.M = 4096; g.N = 512; g.K1 = 512;
    g.A1 = Zs; g.a1 = A_z;                       // W_{c-s}, rows (b, i=c-s)
    g.B = Tm(k); g.ldb = 512;
    g.E1 = Zs + (long)s * 512; g.e1 = A_z; g.beta = 1.0f;
    g.C1 = Zd + (long)s * 512; g.c1 = A_z;
    launchS(g);
    // carry over untouched slots c < s
    copy_rows_k<<<dim3(8 * s), dim3(256), 0, stream>>>(
        Zs, two(k, 262144, s - 1, 512), Zd, two(k, 262144, s - 1, 512),
        16 * s, 128);
  }
  float* Zf = Zb;   // 9 rounds: Za->Zb->...->Zb

  // states[b][c*8] = Zf[b][c];  states[b][2048] = Zf[b][256]
  copy_rows_k<<<dim3(2048), dim3(256), 0, stream>>>(Zf, A_z, states, A_s8,
                                                    4096, 128);
  copy_rows_k<<<dim3(8), dim3(256), 0, stream>>>(Zf + (long)256 * 512, lin(262144),
                                                 states + (long)2048 * 512,
                                                 lin(1049088), 16, 128);

  // ---- corrections (batched): states[b][c*8+j] += Zf[b][c] @ At^j, j=1..7 ----
  {
    GP gs[7];
    for (int j = 1; j <= 7; ++j) {
      GP g = gp0();
      g.M = 4096; g.N = 512; g.K1 = 512;
      g.A1 = Zf; g.a1 = A_z;
      g.B = AP(j); g.ldb = 512;
      g.C2 = states + (long)j * 512; g.c2 = A_s8;
      g.E2 = states + (long)j * 512; g.e2 = A_s8;
      gs[j - 1] = g;
    }
    launchLb(gs, 7);
  }

  // ---- output = states[:, :T] @ Ct + u @ Dt ----
  {
    GP g = gp0();
    g.M = 32768; g.N = 512;
    g.K1 = 512; g.A1 = states; g.a1 = A_srow;
    g.K2 = 512; g.A2 = u; g.a2 = lin(512);
    g.B = CtDt; g.ldb = 512;
    g.C1 = outp; g.c1 = lin(512);
    launchL(g);
  }
}

// Round 7
// 1189.205 us; speedup vs baseline: 1.5879x; 1.2981x over previous
//
#include <hip/hip_runtime.h>
#include <string.h>

typedef _Float16 f16x8 __attribute__((ext_vector_type(8)));
typedef _Float16 f16x4 __attribute__((ext_vector_type(4)));
typedef __fp16   hf2   __attribute__((ext_vector_type(2)));
typedef float    f32x4 __attribute__((ext_vector_type(4)));

// Generic 2-level row addressing: addr(r) = (r>>sh)*hi + (r&msk)*lo   (in elements)
struct Addr { long hi; long lo; int sh; int msk; };

__device__ __forceinline__ long raddr(const Addr a, int r) {
  return ((long)(r >> a.sh)) * a.hi + ((long)(r & a.msk)) * a.lo;
}

struct GP {
  int M, N, K1, K2;
  const float* A1; Addr a1;    // K-segment 1 rows (f32)
  const float* A2; Addr a2;    // K-segment 2 rows (optional, K2>0)
  const float* B;  int ldb;    // BMODE=1: symmetric f32 matrix, staged by rows
  const _Float16* Bh; int ldbh;// BMODE=2: f16 [n][k] pre-transposed operand
  const float* scale;          // optional: alpha *= *scale
  float alpha;
  const float* E1; Addr e1; float beta;   // C1 = alpha*acc + beta*E1
  float* C1; Addr c1;
  _Float16* C1h; int ldh;      // optional f16 transposed shadow of C1 value
  float* C2; Addr c2;          // C2 = alpha*acc + E2
  const float* E2; Addr e2;
  const float* fin;            // 256 partials: stage-scale = 1/sqrt(sum) (BMODE=1)
  float* fout;                 // per-block sum of squares of written values
};

struct GPB { GP g[8]; };

__device__ __forceinline__ f16x4 pk4s(f32x4 v, float ss) {
  hf2 lo = __builtin_amdgcn_cvt_pkrtz(v[0] * ss, v[1] * ss);
  hf2 hi = __builtin_amdgcn_cvt_pkrtz(v[2] * ss, v[3] * ss);
  f16x4 h;
  h[0] = (_Float16)lo[0]; h[1] = (_Float16)lo[1];
  h[2] = (_Float16)hi[0]; h[3] = (_Float16)hi[1];
  return h;
}
__device__ __forceinline__ f16x4 pk4(f32x4 v) {
  hf2 lo = __builtin_amdgcn_cvt_pkrtz(v[0], v[1]);
  hf2 hi = __builtin_amdgcn_cvt_pkrtz(v[2], v[3]);
  f16x4 h;
  h[0] = (_Float16)lo[0]; h[1] = (_Float16)lo[1];
  h[2] = (_Float16)hi[0]; h[3] = (_Float16)hi[1];
  return h;
}

// Tiled GEMM, f32/f16 memory -> f16 LDS -> f32 accum. 4 waves (2x2), single LDS
// buffer, 2-barrier structure with register prefetch (round-5 proven).
// BMODE=1: B = symmetric f32 (staged via row loads, fin-scaled) — squaring chain.
// BMODE=2: B = f16 [n][k] shadow (direct f16x8 row loads, zero VALU).
// Requires (K1+K2) % 64 == 0, N % BN == 0.
template<int BM, int BMODE>
__device__ __forceinline__ void gemm_body(const GP& p) {
  constexpr int BN = BM;
  constexpr int WT = BM / 2;
  constexpr int FM = WT / 16;
  constexpr int NAQ = BM / 32;                  // A f32x4 loads per thread
  constexpr int NBQ = (BMODE == 1) ? BN / 32 : 1;
  constexpr int NBH = (BMODE == 2) ? BN / 64 : 1;
  __shared__ _Float16 As[BM * 40];
  __shared__ _Float16 Bs[BN * 40];
  __shared__ float red[256];
  const int tid = threadIdx.x;
  const int nbn = (p.N + BN - 1) / BN;
  const int nbm = (p.M + BM - 1) / BM;
  if ((int)blockIdx.x >= nbm * nbn) return;
  int bm, bn;
  {
    const int bid = blockIdx.x;
    if ((nbm & 7) == 0) {   // stripe-XCD swizzle
      bm = (bid & 7) + ((bid >> 3) / nbn) * 8;
      bn = (bid >> 3) % nbn;
    } else {
      bm = bid / nbn; bn = bid - bm * nbn;
    }
  }
  const int m0 = bm * BM, n0 = bn * BN;

  float sscale = 1.0f;
  if constexpr (BMODE == 1) {
    if (p.fin) {
      red[tid] = p.fin[tid];
      __syncthreads();
      for (int st = 128; st > 0; st >>= 1) {
        if (tid < st) red[tid] += red[tid + st];
        __syncthreads();
      }
      sscale = 1.0f / sqrtf(red[0]);
      __syncthreads();
    }
  }
  float alpha = p.alpha;
  if (p.scale) alpha *= p.scale[0];

  const int w = tid >> 6, l = tid & 63;
  const int wm = w >> 1, wn = w & 1;
  const int lr = l & 15, lg = l >> 4;

  f32x4 acc[FM][FM];
  #pragma unroll
  for (int m = 0; m < FM; ++m)
    #pragma unroll
    for (int n = 0; n < FM; ++n) acc[m][n] = {0.f, 0.f, 0.f, 0.f};

  const int Kt = p.K1 + p.K2;

  f32x4 aR0[NAQ], aR1[NAQ];
  f32x4 b1R0[NBQ], b1R1[NBQ];
  f16x8 b2R0[NBH], b2R1[NBH];

  auto loadT = [&](int k0, f32x4* aR, f32x4* b1R, f16x8* b2R) {
    const float* Ab; Addr aa; long kl;
    if (k0 < p.K1) { Ab = p.A1; aa = p.a1; kl = k0; }
    else           { Ab = p.A2; aa = p.a2; kl = (long)k0 - p.K1; }
    #pragma unroll
    for (int i = 0; i < NAQ; ++i) {
      const int gq = tid + (i << 8);
      const int ar_ = gq >> 3, kq = gq & 7;
      f32x4 v = {0.f, 0.f, 0.f, 0.f};
      if (m0 + ar_ < p.M) v = *(const f32x4*)(Ab + raddr(aa, m0 + ar_) + kl + kq * 4);
      aR[i] = v;
    }
    if constexpr (BMODE == 2) {
      #pragma unroll
      for (int i = 0; i < NBH; ++i) {
        const int row = (tid >> 2) + i * 64;
        b2R[i] = *(const f16x8*)(p.Bh + (long)(n0 + row) * p.ldbh + k0 + (tid & 3) * 8);
      }
    } else {
      #pragma unroll
      for (int i = 0; i < NBQ; ++i) {
        const int gq = tid + (i << 8);
        const int nr = gq >> 3, kq = gq & 7;
        b1R[i] = *(const f32x4*)(p.B + (long)(n0 + nr) * p.ldb + k0 + kq * 4);
      }
    }
  };
  auto storeLDS = [&](const f32x4* aR, const f32x4* b1R, const f16x8* b2R) {
    #pragma unroll
    for (int i = 0; i < NAQ; ++i) {
      const int gq = tid + (i << 8);
      const int ar_ = gq >> 3, kq = gq & 7;
      f16x4 h = (BMODE == 1) ? pk4s(aR[i], sscale) : pk4(aR[i]);
      *(f16x4*)&As[ar_ * 40 + kq * 4] = h;
    }
    if constexpr (BMODE == 2) {
      #pragma unroll
      for (int i = 0; i < NBH; ++i) {
        const int row = (tid >> 2) + i * 64;
        *(f16x8*)&Bs[row * 40 + (tid & 3) * 8] = b2R[i];
      }
    } else {
      #pragma unroll
      for (int i = 0; i < NBQ; ++i) {
        const int gq = tid + (i << 8);
        const int nr = gq >> 3, kq = gq & 7;
        *(f16x4*)&Bs[nr * 40 + kq * 4] = pk4s(b1R[i], sscale);
      }
    }
  };
  auto compute = [&]() {
    f16x8 a[FM], b[FM];
    #pragma unroll
    for (int m = 0; m < FM; ++m)
      a[m] = *(const f16x8*)&As[(wm * WT + m * 16 + lr) * 40 + lg * 8];
    #pragma unroll
    for (int n = 0; n < FM; ++n)
      b[n] = *(const f16x8*)&Bs[(wn * WT + n * 16 + lr) * 40 + lg * 8];
    #pragma unroll
    for (int m = 0; m < FM; ++m)
      #pragma unroll
      for (int n = 0; n < FM; ++n)
        acc[m][n] = __builtin_amdgcn_mfma_f32_16x16x32_f16(a[m], b[n], acc[m][n], 0, 0, 0);
  };

  loadT(0, aR0, b1R0, b2R0);
  for (int k0 = 0; k0 < Kt; k0 += 64) {
    storeLDS(aR0, b1R0, b2R0);
    __syncthreads();
    loadT(k0 + 32, aR1, b1R1, b2R1);   // prefetch overlaps compute
    compute();
    __syncthreads();
    storeLDS(aR1, b1R1, b2R1);
    __syncthreads();
    if (k0 + 64 < Kt) loadT(k0 + 64, aR0, b1R0, b2R0);
    compute();
    __syncthreads();
  }

  float ssq = 0.0f;
  #pragma unroll
  for (int m = 0; m < FM; ++m) {
    #pragma unroll
    for (int n = 0; n < FM; ++n) {
      #pragma unroll
      for (int rr = 0; rr < 4; ++rr) {
        const int ro = m0 + wm * WT + m * 16 + lg * 4 + rr;
        const int no = n0 + wn * WT + n * 16 + lr;
        if (ro < p.M) {
          float val = alpha * acc[m][n][rr];
          float o1 = val;
          if (p.E1) o1 += p.beta * p.E1[raddr(p.e1, ro) + no];
          if (p.C1) p.C1[raddr(p.c1, ro) + no] = o1;
          if (p.C1h) p.C1h[(long)no * p.ldh + ro] = (_Float16)o1;
          if (p.C2) p.C2[raddr(p.c2, ro) + no] = val + p.E2[raddr(p.e2, ro) + no];
          ssq += val * val;
        }
      }
    }
  }
  if (p.fout) {
    __syncthreads();
    red[tid] = ssq;
    __syncthreads();
    for (int st = 128; st > 0; st >>= 1) {
      if (tid < st) red[tid] += red[tid + st];
      __syncthreads();
    }
    if (tid == 0) p.fout[blockIdx.x] = red[0];
  }
}

__global__ __launch_bounds__(256) void gemm_S1(GPB pb) { gemm_body<64, 1>(pb.g[blockIdx.y]); }
__global__ __launch_bounds__(256) void gemm_S2(GPB pb) { gemm_body<64, 2>(pb.g[blockIdx.y]); }
__global__ __launch_bounds__(256) void gemm_L2(GPB pb) { gemm_body<128, 2>(pb.g[blockIdx.y]); }

// out[i][j] = diag*(i==j) + sgn*mult*(*scale)*in[(roff+j)*ld + coff+i]   (f32)
__global__ void tr_k(const float* in, long ld, long roff, long coff,
                     float* out, int n, const float* scale,
                     float mult, float diag, float sgn) {
  __shared__ float t[32][33];
  const int nb = n >> 5;
  const int bx = blockIdx.x % nb, by = blockIdx.x / nb;
  const long I0 = (long)bx * 32, J0 = (long)by * 32;
  const int tx = threadIdx.x, ty = threadIdx.y;
  #pragma unroll
  for (int k = 0; k < 4; ++k)
    t[ty * 4 + k][tx] = in[(roff + J0 + ty * 4 + k) * ld + coff + I0 + tx];
  __syncthreads();
  const float sc = scale ? scale[0] : 1.0f;
  const float f = sgn * mult * sc;
  #pragma unroll
  for (int k = 0; k < 4; ++k) {
    const long i = I0 + ty * 4 + k, j = J0 + tx;
    out[i * n + j] = ((i == j) ? diag : 0.0f) + f * t[tx][ty * 4 + k];
  }
}

// f16 transpose: out[i][j] = (f16) in[j][i]   (n x n)
__global__ void trh_k(const float* in, int n, _Float16* out) {
  __shared__ float t[32][33];
  const int nb = n >> 5;
  const int bx = blockIdx.x % nb, by = blockIdx.x / nb;
  const long I0 = (long)bx * 32, J0 = (long)by * 32;
  const int tx = threadIdx.x, ty = threadIdx.y;
  #pragma unroll
  for (int k = 0; k < 4; ++k)
    t[ty * 4 + k][tx] = in[(J0 + ty * 4 + k) * n + I0 + tx];
  __syncthreads();
  #pragma unroll
  for (int k = 0; k < 4; ++k) {
    const long i = I0 + ty * 4 + k, j = J0 + tx;
    out[i * n + j] = (_Float16)t[tx][ty * 4 + k];
  }
}

// f16 scale-copy (512x512): out[i*ldo+j] = diag*(i==j) + mult*(*scale)*in[(roff+i)*ld + coff+j]
__global__ void sc_k(const float* in, long ld, long roff, long coff,
                     _Float16* out, int ldo, const float* scale,
                     float mult, float diag) {
  const int idx = blockIdx.x * 256 + threadIdx.x;
  const int i = idx >> 9, j = idx & 511;
  const float f = mult * (scale ? scale[0] : 1.0f);
  out[(long)i * ldo + j] =
      (_Float16)(((i == j) ? diag : 0.0f) + f * in[(roff + i) * ld + coff + j]);
}

__global__ void copy_rows_k(const float* src, Addr sa, float* dst, Addr da,
                            int M, int N4) {
  const long idx = (long)blockIdx.x * 256 + threadIdx.x;
  if (idx >= (long)M * N4) return;
  const int r = (int)(idx / N4);
  const long q = (idx - (long)r * N4) * 4;
  *(f32x4*)(dst + raddr(da, r) + q) = *(const f32x4*)(src + raddr(sa, r) + q);
}

// sigma from scale chain: ln l1(M0) = sum_{k<nsq} 2^-k ln s_k + 2^-nsq ln s_nsq
__global__ void scalar_k(const float* P, int nsq, const float* lg, float* sc) {
  __shared__ float red[256];
  __shared__ float sv[16];
  const int tid = threadIdx.x;
  for (int k = 0; k <= nsq; ++k) {
    red[tid] = P[k * 256 + tid];
    __syncthreads();
    for (int st = 128; st > 0; st >>= 1) {
      if (tid < st) red[tid] += red[tid + st];
      __syncthreads();
    }
    if (tid == 0) sv[k] = red[0];
    __syncthreads();
  }
  if (tid != 0) return;
  double lnl = 0.0, wgt = 1.0;
  for (int k = 0; k <= nsq; ++k) {
    double sk = sqrt((double)sv[k]);
    lnl += wgt * log(sk);
    if (k < nsq) wgt *= 0.5;
  }
  double sigma = exp(0.5 * lnl);
  if (sigma < 1e-5) sigma = 1e-5;
  const double invk = 1.0 / (sigma + 0.002);
  const double g = exp((double)lg[0]);
  sc[0] = (float)invk;        // invk
  sc[1] = (float)g;           // gamma
  sc[2] = (float)(g * invk);  // gamma*invk
}

static inline Addr lin(long stride) {
  Addr a; a.hi = 0; a.lo = stride; a.sh = 20; a.msk = 0xFFFFF; return a;
}
static inline Addr two(int sh, long hi, int msk, long lo) {
  Addr a; a.hi = hi; a.lo = lo; a.sh = sh; a.msk = msk; return a;
}
static inline GP gp0() {
  GP p; memset(&p, 0, sizeof(p)); p.alpha = 1.0f; p.beta = 1.0f; return p;
}

extern "C" void kernel_launch(void* const* d_in, const int* in_sizes, int n_in,
                              void* d_out, int out_size, void* d_ws, size_t ws_size,
                              hipStream_t stream) {
  (void)in_sizes; (void)n_in; (void)out_size; (void)ws_size;
  const float* u    = (const float*)d_in[0];  // [16][2048][512]
  const float* st0  = (const float*)d_in[1];  // [16][512]
  const float* S    = (const float*)d_in[2];  // [512][512]
  const float* Kr   = (const float*)d_in[3];  // [1024][1024]
  const float* lgam = (const float*)d_in[4];  // [1]

  float* outp   = (float*)d_out;                       // [16][2048][512]
  float* states = outp + (long)16 * 2048 * 512;        // [16][2049][512]
  float* ws = (float*)d_ws;

  const int NSQ = 12;
  float* sc = ws;                 // 3 scalars
  float* P  = ws + 64;            // (NSQ+1)*256 frobenius partials
  float* base = ws + 3456;

  // region1 (dead after scalar kernel)
  float* Krt = base;                  // 1024^2
  float* Ma  = base + 1048576;        // 1024^2
  float* Mb  = base + 2097152;        // 1024^2
  // region2 (overlaps region1; first written after scalar_k)
  float* St   = base;                 // 512^2 each below
  float* Xa   = base + 262144;
  float* Xb   = base + 524288;
  float* Yn   = base + 786432;
  float* K11t = base + 1048576;
  float* K12t = base + 1310720;
  float* ABst = base + 1572864;       // At f32 512x512 (A-operand uses only)
  // CtDtH f16 [512][1024] in ws (read while outp is being written)
  _Float16* CtDtH = (_Float16*)(ws + 3149248);

  // big f32 scratch in outp region (dead before final GEMM writes)
  float* Za  = outp;                  // [16][512][512] Kogge-Stone ping
  float* Zb  = outp + 4194304;        // [16][512][512] Kogge-Stone pong
  float* APb = outp + 8388608;        // At^j f32, j=2..8 : APb+(j-2)*262144
  float* Tb  = outp + 10223616;       // Q^(2^k) f32, k=1..8 : Tb+(k-1)*262144
  // f16 shadows in outp tail (elem 12320768.. ; not touched by Za/Zb/APb/Tb)
  _Float16* h16   = (_Float16*)(outp + 12320768);
  _Float16* ABstH = h16;                       // [512][1024]: AtH | BtH
  _Float16* APH_  = h16 + 524288;              // j=2..8, [512][512]
  _Float16* TmH_  = h16 + 2359296;             // k=1..8, [512][512]
  _Float16* XaH   = h16 + 4456448;
  _Float16* XbH   = XaH + 262144;
  _Float16* YnH   = XbH + 262144;
  _Float16* WH    = YnH + 262144;
  _Float16* K21tH = WH + 262144;
  _Float16* KrH   = K21tH + 262144;            // [1024][1024]

  auto APf = [&](int j) -> float* {            // f32 powers (A-operands)
    return (j == 1) ? ABst : APb + (long)(j - 2) * 262144;
  };
  auto APH = [&](int j) -> _Float16* {
    return (j == 1) ? ABstH : APH_ + (long)(j - 2) * 262144;
  };
  auto APHld = [&](int j) { return (j == 1) ? 1024 : 512; };
  auto Tmf = [&](int k) -> float* { return (k == 0) ? APf(8) : Tb + (long)(k - 1) * 262144; };
  auto TmH = [&](int k) -> _Float16* { return (k == 0) ? APH(8) : TmH_ + (long)(k - 1) * 262144; };

  auto launchS1b = [&](const GP* gs, int nb) {
    GPB pb; memset(&pb, 0, sizeof(pb));
    int mx = 0;
    for (int i = 0; i < nb; ++i) {
      pb.g[i] = gs[i];
      int b = ((gs[i].M + 63) / 64) * ((gs[i].N + 63) / 64);
      if (b > mx) mx = b;
    }
    gemm_S1<<<dim3(mx, nb), dim3(256), 0, stream>>>(pb);
  };
  auto launchS2b = [&](const GP* gs, int nb) {
    GPB pb; memset(&pb, 0, sizeof(pb));
    int mx = 0;
    for (int i = 0; i < nb; ++i) {
      pb.g[i] = gs[i];
      int b = ((gs[i].M + 63) / 64) * ((gs[i].N + 63) / 64);
      if (b > mx) mx = b;
    }
    gemm_S2<<<dim3(mx, nb), dim3(256), 0, stream>>>(pb);
  };
  auto launchS1 = [&](const GP& g) { launchS1b(&g, 1); };
  auto launchS2 = [&](const GP& g) { launchS2b(&g, 1); };
  auto launchL2b = [&](const GP* gs, int nb) {
    GPB pb; memset(&pb, 0, sizeof(pb));
    int mx = 0;
    for (int i = 0; i < nb; ++i) {
      pb.g[i] = gs[i];
      int b = ((gs[i].M + 127) / 128) * ((gs[i].N + 127) / 128);
      if (b > mx) mx = b;
    }
    gemm_L2<<<dim3(mx, nb), dim3(256), 0, stream>>>(pb);
  };
  auto launchL2 = [&](const GP& g) { launchL2b(&g, 1); };

  // mode-2 512^3 product helper: C f32 (optional) + C1h f16 shadow
  auto mmh = [&](const float* A, const _Float16* Bh, int ldbh,
                 float* C, _Float16* Ch, int ldh) {
    GP g = gp0(); g.M = 512; g.N = 512; g.K1 = 512;
    g.A1 = A; g.a1 = lin(512);
    g.Bh = Bh; g.ldbh = ldbh;
    g.C1 = C; g.c1 = lin(512);
    g.C1h = Ch; g.ldh = ldh;
    return g;
  };

  // ---- Phase A: sigma via squaring chain ----
  tr_k<<<dim3(1024), dim3(32, 8), 0, stream>>>(Kr, 1024, 0, 0, Krt, 1024,
                                               nullptr, 1.f, 0.f, 1.f);
  trh_k<<<dim3(1024), dim3(32, 8), 0, stream>>>(Kr, 1024, KrH);
  {
    GP g = gp0();
    g.M = 1024; g.N = 1024; g.K1 = 1024;
    g.A1 = Krt; g.a1 = lin(1024);
    g.Bh = KrH; g.ldbh = 1024;
    g.C1 = Ma; g.c1 = lin(1024);
    g.fout = P;
    launchS2(g);               // M0 = Kr^T Kr, partials P0
  }
  {
    float* cur = Ma; float* nxt = Mb;
    for (int k = 1; k <= NSQ; ++k) {
      GP g = gp0();
      g.M = 1024; g.N = 1024; g.K1 = 1024;
      g.A1 = cur; g.a1 = lin(1024);
      g.B = cur; g.ldb = 1024;         // symmetric: row-staged
      g.C1 = nxt; g.c1 = lin(1024);
      g.fin = P + (long)(k - 1) * 256;
      g.fout = P + (long)k * 256;
      launchS1(g);             // M_k = (M_{k-1}/s_{k-1})^2
      float* t = cur; cur = nxt; nxt = t;
    }
  }
  scalar_k<<<1, 256, 0, stream>>>(P, NSQ, lgam, sc);

  // ---- transposes / f16 shadows (region2 overwrites region1 from here) ----
  tr_k<<<dim3(256), dim3(32, 8), 0, stream>>>(S, 512, 0, 0, St, 512,
                                              nullptr, 1.f, 0.f, 1.f);     // St = S^T
  tr_k<<<dim3(256), dim3(32, 8), 0, stream>>>(S, 512, 0, 0, Xa, 512,
                                              nullptr, 1.f, 2.f, -1.f);    // X0 = 2I - S^T
  tr_k<<<dim3(256), dim3(32, 8), 0, stream>>>(Kr, 1024, 0, 0, K11t, 512,
                                              sc, 1.f, 0.f, 1.f);          // K11^T * invk
  tr_k<<<dim3(256), dim3(32, 8), 0, stream>>>(Kr, 1024, 0, 512, K12t, 512,
                                              sc, 1.f, 0.f, 1.f);          // K12^T * invk
  sc_k<<<dim3(1024), dim3(256), 0, stream>>>(S, 512, 0, 0, XaH, 512,
                                             nullptr, -1.f, 2.f);          // X0H = 2I - S
  sc_k<<<dim3(1024), dim3(256), 0, stream>>>(Kr, 1024, 512, 0, K21tH, 512,
                                             sc, 1.f, 0.f);                // invk*K21
  sc_k<<<dim3(1024), dim3(256), 0, stream>>>(Kr, 1024, 512, 512, CtDtH + 512, 1024,
                                             sc + 2, 1.f, 0.f);            // DtH = g*invk*K22

  // ---- Newton: SinvT = (S^T)^-1, 3 iterations -> Xb/XbH ----
  for (int k = 0; k < 3; ++k) {
    float* cur = (k % 2 == 0) ? Xa : Xb;
    float* nxt = (k % 2 == 0) ? Xb : Xa;
    _Float16* curH = (k % 2 == 0) ? XaH : XbH;
    _Float16* nxtH = (k % 2 == 0) ? XbH : XaH;
    { GP g = mmh(St, curH, 512, Yn, YnH, 512); launchS2(g); }   // Yn = St@X
    GP h = mmh(cur, YnH, 512, nxt, nxtH, 512);
    h.alpha = -1.0f;
    h.E1 = cur; h.e1 = lin(512); h.beta = 2.0f;
    launchS2(h);               // X' = 2X - X@Yn
  }

  // ---- {W, Ct} then {At, Bt} ----
  {
    GP gs[2];
    gs[0] = mmh(K11t, XbH, 512, nullptr, WH, 512);        // W = K11t @ SinvT
    gs[1] = mmh(St, K21tH, 512, nullptr, CtDtH, 1024);    // CtH = (St @ K21t)^T
    launchS2b(gs, 2);
  }
  {
    GP gs[2];
    gs[0] = mmh(St, WH, 512, ABst, ABstH, 1024);          // At (+AtH)
    gs[1] = mmh(K12t, XbH, 512, nullptr, ABstH + 512, 1024); // BtH = gamma*(K12t@SinvT)^T
    gs[1].scale = sc + 1;
    launchS2b(gs, 2);
  }

  // ---- At powers j=2..8 via doubling ----
  { GP g = mmh(APf(1), APH(1), 1024, APf(2), APH(2), 512); launchS2(g); }
  { GP gs[2] = { mmh(APf(2), APH(1), 1024, APf(3), APH(3), 512),
                 mmh(APf(2), APH(2), 512,  APf(4), APH(4), 512) };
    launchS2b(gs, 2); }
  { GP gs[4];
    for (int i = 1; i <= 4; ++i)
      gs[i - 1] = mmh(APf(4), APH(i), APHld(i), APf(4 + i), APH(4 + i), 512);
    launchS2b(gs, 4); }

  // ---- T(k) = Q^(2^k), Q = At^8 ----
  for (int k = 1; k <= 8; ++k) {
    GP g = mmh(Tmf(k - 1), TmH(k - 1), 512, Tmf(k), TmH(k), 512);
    launchS2(g);
  }

  // Addressing constants (L=8, 256 chunks/batch)
  const Addr A_u8   = two(8, 1048576, 255, 4096);   // u[b][8c] rows, r=(b<<8)|c
  const Addr A_s8   = two(8, 1049088, 255, 4096);   // states[b][8c] rows
  const Addr A_z    = two(8, 262144, 255, 512);     // Z[b][c] slots (512-slot pad)
  const Addr A_srow = two(11, 1049088, 2047, 512);  // states[b][t]

  // Z init: slot (b,0) = initial state
  copy_rows_k<<<dim3(8), dim3(256), 0, stream>>>(st0, lin(512), Za, lin(262144),
                                                 16, 128);

  // ---- pass1: local zero-init scans; l_j -> states slot c*8+j (j=1..7), l_8 -> Za[c+1]
  for (int j = 1; j <= 8; ++j) {
    GP g = gp0();
    g.M = 4096; g.N = 512;
    if (j == 1) {
      g.K1 = 512; g.A1 = u; g.a1 = A_u8;
      g.Bh = ABstH + 512; g.ldbh = 1024;   // Bt only
    } else {
      g.K1 = 512; g.A1 = states + (long)(j - 1) * 512; g.a1 = A_s8;
      g.K2 = 512; g.A2 = u + (long)(j - 1) * 512; g.a2 = A_u8;
      g.Bh = ABstH; g.ldbh = 1024;         // [At; Bt]
    }
    if (j == 8) { g.C1 = Za + 512; g.c1 = A_z; }
    else { g.C1 = states + (long)j * 512; g.c1 = A_s8; }
    launchS2(g);
  }

  // ---- Kogge-Stone weighted prefix over 257 chunk states ----
  for (int k = 0; k <= 8; ++k) {
    const int s = 1 << k;
    float* Zs = (k % 2 == 0) ? Za : Zb;
    float* Zd = (k % 2 == 0) ? Zb : Za;
    GP g = gp0();
    g.M = 4096; g.N = 512; g.K1 = 512;
    g.A1 = Zs; g.a1 = A_z;
    g.Bh = TmH(k); g.ldbh = 512;
    g.E1 = Zs + (long)s * 512; g.e1 = A_z; g.beta = 1.0f;
    g.C1 = Zd + (long)s * 512; g.c1 = A_z;
    launchS2(g);
    copy_rows_k<<<dim3(8 * s), dim3(256), 0, stream>>>(
        Zs, two(k, 262144, s - 1, 512), Zd, two(k, 262144, s - 1, 512),
        16 * s, 128);
  }
  float* Zf = Zb;

  // states[b][c*8] = Zf[b][c];  states[b][2048] = Zf[b][256]
  copy_rows_k<<<dim3(2048), dim3(256), 0, stream>>>(Zf, A_z, states, A_s8,
                                                    4096, 128);
  copy_rows_k<<<dim3(8), dim3(256), 0, stream>>>(Zf + (long)256 * 512, lin(262144),
                                                 states + (long)2048 * 512,
                                                 lin(1049088), 16, 128);

  // ---- corrections (batched): states[b][c*8+j] += Zf[b][c] @ At^j, j=1..7 ----
  {
    GP gs[7];
    for (int j = 1; j <= 7; ++j) {
      GP g = gp0();
      g.M = 4096; g.N = 512; g.K1 = 512;
      g.A1 = Zf; g.a1 = A_z;
      g.Bh = APH(j); g.ldbh = APHld(j);
      g.C2 = states + (long)j * 512; g.c2 = A_s8;
      g.E2 = states + (long)j * 512; g.e2 = A_s8;
      gs[j - 1] = g;
    }
    launchL2b(gs, 7);
  }

  // ---- output = states[:, :T] @ Ct + u @ Dt ----
  {
    GP g = gp0();
    g.M = 32768; g.N = 512;
    g.K1 = 512; g.A1 = states; g.a1 = A_srow;
    g.K2 = 512; g.A2 = u; g.a2 = lin(512);
    g.Bh = CtDtH; g.ldbh = 1024;
    g.C1 = outp; g.c1 = lin(512);
    launchL2(g);
  }
}

// Round 8
// 947.307 us; speedup vs baseline: 1.9933x; 1.2554x over previous
//
#include <hip/hip_runtime.h>
#include <string.h>

typedef _Float16 f16x8 __attribute__((ext_vector_type(8)));
typedef _Float16 f16x4 __attribute__((ext_vector_type(4)));
typedef __fp16   hf2   __attribute__((ext_vector_type(2)));
typedef float    f32x4 __attribute__((ext_vector_type(4)));

// Generic 2-level row addressing: addr(r) = (r>>sh)*hi + (r&msk)*lo   (in elements)
struct Addr { long hi; long lo; int sh; int msk; };

__device__ __forceinline__ long raddr(const Addr a, int r) {
  return ((long)(r >> a.sh)) * a.hi + ((long)(r & a.msk)) * a.lo;
}

struct GP {
  int M, N, K1, K2;
  const float* A1; Addr a1;    // K-segment 1 rows (f32)
  const float* A2; Addr a2;    // K-segment 2 rows (optional, K2>0)
  const float* B;  int ldb;    // mode-1 (Bh==null): symmetric f32 B, row-staged
  const _Float16* Bh; int ldbh;// mode-2: f16 [n][k] pre-transposed operand
  const float* scale;          // optional: alpha *= *scale
  float alpha;
  const float* E1; Addr e1; float beta;   // C1 = alpha*acc + beta*E1
  float* C1; Addr c1;
  _Float16* C1h; int ldh;      // optional f16 transposed shadow of C1 value
  float* C2; Addr c2;          // C2 = alpha*acc + E2
  const float* E2; Addr e2;
  const float* fin;            // 256 partials: stage-scale = 1/sqrt(sum) (mode-1)
  float* fout;                 // per-block sum of squares of written values
};

struct GPB { GP g[10]; };

__device__ __forceinline__ f16x4 pk4s(f32x4 v, float ss) {
  hf2 lo = __builtin_amdgcn_cvt_pkrtz(v[0] * ss, v[1] * ss);
  hf2 hi = __builtin_amdgcn_cvt_pkrtz(v[2] * ss, v[3] * ss);
  f16x4 h;
  h[0] = (_Float16)lo[0]; h[1] = (_Float16)lo[1];
  h[2] = (_Float16)hi[0]; h[3] = (_Float16)hi[1];
  return h;
}

// Unified tiled GEMM, f32/f16 memory -> f16 LDS -> f32 accum. 4 waves (2x2),
// single LDS buffer, 2-barrier structure with register prefetch.
// Per-GP runtime mode: Bh!=null -> f16 [n][k] B rows; else symmetric f32 B.
// Requires (K1+K2) % 64 == 0, N % BN == 0.
template<int BM, bool M1EN>
__device__ __forceinline__ void gemm_body(const GP& p) {
  constexpr int BN = BM;
  constexpr int WT = BM / 2;
  constexpr int FM = WT / 16;
  constexpr int NAQ = BM / 32;                   // A f32x4 loads per thread
  constexpr int NBQ = M1EN ? BN / 32 : 1;        // mode-1 B f32x4 loads
  constexpr int NBH = BN / 64;                   // mode-2 B f16x8 loads
  __shared__ _Float16 As[BM * 40];
  __shared__ _Float16 Bs[BN * 40];
  __shared__ float red[256];
  const int tid = threadIdx.x;
  const int nbn = (p.N + BN - 1) / BN;
  const int nbm = (p.M + BM - 1) / BM;
  if ((int)blockIdx.x >= nbm * nbn) return;
  int bm, bn;
  {
    const int bid = blockIdx.x;
    if ((nbm & 7) == 0) {   // stripe-XCD swizzle
      bm = (bid & 7) + ((bid >> 3) / nbn) * 8;
      bn = (bid >> 3) % nbn;
    } else {
      bm = bid / nbn; bn = bid - bm * nbn;
    }
  }
  const int m0 = bm * BM, n0 = bn * BN;
  const bool hmode = M1EN ? (p.Bh != nullptr) : true;

  float sscale = 1.0f;
  if (M1EN && p.fin) {
    red[tid] = p.fin[tid];
    __syncthreads();
    for (int st = 128; st > 0; st >>= 1) {
      if (tid < st) red[tid] += red[tid + st];
      __syncthreads();
    }
    sscale = 1.0f / sqrtf(red[0]);
    __syncthreads();
  }
  float alpha = p.alpha;
  if (p.scale) alpha *= p.scale[0];

  const int w = tid >> 6, l = tid & 63;
  const int wm = w >> 1, wn = w & 1;
  const int lr = l & 15, lg = l >> 4;

  f32x4 acc[FM][FM];
  #pragma unroll
  for (int m = 0; m < FM; ++m)
    #pragma unroll
    for (int n = 0; n < FM; ++n) acc[m][n] = {0.f, 0.f, 0.f, 0.f};

  const int Kt = p.K1 + p.K2;

  f32x4 aR0[NAQ], aR1[NAQ];
  f32x4 b1R0[NBQ], b1R1[NBQ];
  f16x8 b2R0[NBH], b2R1[NBH];

  auto loadT = [&](int k0, f32x4* aR, f32x4* b1R, f16x8* b2R) {
    const float* Ab; Addr aa; long kl;
    if (k0 < p.K1) { Ab = p.A1; aa = p.a1; kl = k0; }
    else           { Ab = p.A2; aa = p.a2; kl = (long)k0 - p.K1; }
    #pragma unroll
    for (int i = 0; i < NAQ; ++i) {
      const int gq = tid + (i << 8);
      const int ar_ = gq >> 3, kq = gq & 7;
      f32x4 v = {0.f, 0.f, 0.f, 0.f};
      if (m0 + ar_ < p.M) v = *(const f32x4*)(Ab + raddr(aa, m0 + ar_) + kl + kq * 4);
      aR[i] = v;
    }
    if (hmode) {
      #pragma unroll
      for (int i = 0; i < NBH; ++i) {
        const int row = (tid >> 2) + i * 64;
        b2R[i] = *(const f16x8*)(p.Bh + (long)(n0 + row) * p.ldbh + k0 + (tid & 3) * 8);
      }
    } else if (M1EN) {
      #pragma unroll
      for (int i = 0; i < NBQ; ++i) {
        const int gq = tid + (i << 8);
        const int nr = gq >> 3, kq = gq & 7;
        b1R[i] = *(const f32x4*)(p.B + (long)(n0 + nr) * p.ldb + k0 + kq * 4);
      }
    }
  };
  auto storeLDS = [&](const f32x4* aR, const f32x4* b1R, const f16x8* b2R) {
    #pragma unroll
    for (int i = 0; i < NAQ; ++i) {
      const int gq = tid + (i << 8);
      const int ar_ = gq >> 3, kq = gq & 7;
      *(f16x4*)&As[ar_ * 40 + kq * 4] = pk4s(aR[i], sscale);
    }
    if (hmode) {
      #pragma unroll
      for (int i = 0; i < NBH; ++i) {
        const int row = (tid >> 2) + i * 64;
        *(f16x8*)&Bs[row * 40 + (tid & 3) * 8] = b2R[i];
      }
    } else if (M1EN) {
      #pragma unroll
      for (int i = 0; i < NBQ; ++i) {
        const int gq = tid + (i << 8);
        const int nr = gq >> 3, kq = gq & 7;
        *(f16x4*)&Bs[nr * 40 + kq * 4] = pk4s(b1R[i], sscale);
      }
    }
  };
  auto compute = [&]() {
    f16x8 a[FM], b[FM];
    #pragma unroll
    for (int m = 0; m < FM; ++m)
      a[m] = *(const f16x8*)&As[(wm * WT + m * 16 + lr) * 40 + lg * 8];
    #pragma unroll
    for (int n = 0; n < FM; ++n)
      b[n] = *(const f16x8*)&Bs[(wn * WT + n * 16 + lr) * 40 + lg * 8];
    #pragma unroll
    for (int m = 0; m < FM; ++m)
      #pragma unroll
      for (int n = 0; n < FM; ++n)
        acc[m][n] = __builtin_amdgcn_mfma_f32_16x16x32_f16(a[m], b[n], acc[m][n], 0, 0, 0);
  };

  loadT(0, aR0, b1R0, b2R0);
  for (int k0 = 0; k0 < Kt; k0 += 64) {
    storeLDS(aR0, b1R0, b2R0);
    __syncthreads();
    loadT(k0 + 32, aR1, b1R1, b2R1);   // prefetch overlaps compute
    compute();
    __syncthreads();
    storeLDS(aR1, b1R1, b2R1);
    __syncthreads();
    if (k0 + 64 < Kt) loadT(k0 + 64, aR0, b1R0, b2R0);
    compute();
    __syncthreads();
  }

  float ssq = 0.0f;
  #pragma unroll
  for (int m = 0; m < FM; ++m) {
    #pragma unroll
    for (int n = 0; n < FM; ++n) {
      #pragma unroll
      for (int rr = 0; rr < 4; ++rr) {
        const int ro = m0 + wm * WT + m * 16 + lg * 4 + rr;
        const int no = n0 + wn * WT + n * 16 + lr;
        if (ro < p.M) {
          float val = alpha * acc[m][n][rr];
          float o1 = val;
          if (p.E1) o1 += p.beta * p.E1[raddr(p.e1, ro) + no];
          if (p.C1) p.C1[raddr(p.c1, ro) + no] = o1;
          if (p.C1h) p.C1h[(long)no * p.ldh + ro] = (_Float16)o1;
          if (p.C2) p.C2[raddr(p.c2, ro) + no] = val + p.E2[raddr(p.e2, ro) + no];
          ssq += val * val;
        }
      }
    }
  }
  if (p.fout) {
    __syncthreads();
    red[tid] = ssq;
    __syncthreads();
    for (int st = 128; st > 0; st >>= 1) {
      if (tid < st) red[tid] += red[tid + st];
      __syncthreads();
    }
    if (tid == 0) p.fout[blockIdx.x] = red[0];
  }
}

__global__ __launch_bounds__(256) void gemm_u64(GPB pb)  { gemm_body<64, true>(pb.g[blockIdx.y]); }
__global__ __launch_bounds__(256) void gemm_u128(GPB pb) { gemm_body<128, false>(pb.g[blockIdx.y]); }

// out[i][j] = diag*(i==j) + sgn*mult*(*scale)*in[(roff+j)*ld + coff+i]   (f32)
__global__ void tr_k(const float* in, long ld, long roff, long coff,
                     float* out, int n, const float* scale,
                     float mult, float diag, float sgn) {
  __shared__ float t[32][33];
  const int nb = n >> 5;
  const int bx = blockIdx.x % nb, by = blockIdx.x / nb;
  const long I0 = (long)bx * 32, J0 = (long)by * 32;
  const int tx = threadIdx.x, ty = threadIdx.y;
  #pragma unroll
  for (int k = 0; k < 4; ++k)
    t[ty * 4 + k][tx] = in[(roff + J0 + ty * 4 + k) * ld + coff + I0 + tx];
  __syncthreads();
  const float sc = scale ? scale[0] : 1.0f;
  const float f = sgn * mult * sc;
  #pragma unroll
  for (int k = 0; k < 4; ++k) {
    const long i = I0 + ty * 4 + k, j = J0 + tx;
    out[i * n + j] = ((i == j) ? diag : 0.0f) + f * t[tx][ty * 4 + k];
  }
}

// f16 transpose: out[i][j] = (f16) in[j][i]   (n x n)
__global__ void trh_k(const float* in, int n, _Float16* out) {
  __shared__ float t[32][33];
  const int nb = n >> 5;
  const int bx = blockIdx.x % nb, by = blockIdx.x / nb;
  const long I0 = (long)bx * 32, J0 = (long)by * 32;
  const int tx = threadIdx.x, ty = threadIdx.y;
  #pragma unroll
  for (int k = 0; k < 4; ++k)
    t[ty * 4 + k][tx] = in[(J0 + ty * 4 + k) * n + I0 + tx];
  __syncthreads();
  #pragma unroll
  for (int k = 0; k < 4; ++k) {
    const long i = I0 + ty * 4 + k, j = J0 + tx;
    out[i * n + j] = (_Float16)t[tx][ty * 4 + k];
  }
}

// f16 scale-copy (512x512): out[i*ldo+j] = diag*(i==j) + mult*(*scale)*in[(roff+i)*ld + coff+j]
__global__ void sc_k(const float* in, long ld, long roff, long coff,
                     _Float16* out, int ldo, const float* scale,
                     float mult, float diag) {
  const int idx = blockIdx.x * 256 + threadIdx.x;
  const int i = idx >> 9, j = idx & 511;
  const float f = mult * (scale ? scale[0] : 1.0f);
  out[(long)i * ldo + j] =
      (_Float16)(((i == j) ? diag : 0.0f) + f * in[(roff + i) * ld + coff + j]);
}

__global__ void copy_rows_k(const float* src, Addr sa, float* dst, Addr da,
                            int M, int N4) {
  const long idx = (long)blockIdx.x * 256 + threadIdx.x;
  if (idx >= (long)M * N4) return;
  const int r = (int)(idx / N4);
  const long q = (idx - (long)r * N4) * 4;
  *(f32x4*)(dst + raddr(da, r) + q) = *(const f32x4*)(src + raddr(sa, r) + q);
}

// sigma from scale chain: ln l1(M0) = sum_{k<nsq} 2^-k ln s_k + 2^-nsq ln s_nsq
__global__ void scalar_k(const float* P, int nsq, const float* lg, float* sc) {
  __shared__ float red[256];
  __shared__ float sv[16];
  const int tid = threadIdx.x;
  for (int k = 0; k <= nsq; ++k) {
    red[tid] = P[k * 256 + tid];
    __syncthreads();
    for (int st = 128; st > 0; st >>= 1) {
      if (tid < st) red[tid] += red[tid + st];
      __syncthreads();
    }
    if (tid == 0) sv[k] = red[0];
    __syncthreads();
  }
  if (tid != 0) return;
  double lnl = 0.0, wgt = 1.0;
  for (int k = 0; k <= nsq; ++k) {
    double sk = sqrt((double)sv[k]);
    lnl += wgt * log(sk);
    if (k < nsq) wgt *= 0.5;
  }
  double sigma = exp(0.5 * lnl);
  if (sigma < 1e-5) sigma = 1e-5;
  const double invk = 1.0 / (sigma + 0.002);
  const double g = exp((double)lg[0]);
  sc[0] = (float)invk;        // invk
  sc[1] = (float)g;           // gamma
  sc[2] = (float)(g * invk);  // gamma*invk
}

static inline Addr lin(long stride) {
  Addr a; a.hi = 0; a.lo = stride; a.sh = 20; a.msk = 0xFFFFF; return a;
}
static inline Addr two(int sh, long hi, int msk, long lo) {
  Addr a; a.hi = hi; a.lo = lo; a.sh = sh; a.msk = msk; return a;
}
static inline GP gp0() {
  GP p; memset(&p, 0, sizeof(p)); p.alpha = 1.0f; p.beta = 1.0f; return p;
}

extern "C" void kernel_launch(void* const* d_in, const int* in_sizes, int n_in,
                              void* d_out, int out_size, void* d_ws, size_t ws_size,
                              hipStream_t stream) {
  (void)in_sizes; (void)n_in; (void)out_size; (void)ws_size;
  const float* u    = (const float*)d_in[0];  // [16][2048][512]
  const float* st0  = (const float*)d_in[1];  // [16][512]
  const float* S    = (const float*)d_in[2];  // [512][512]
  const float* Kr   = (const float*)d_in[3];  // [1024][1024]
  const float* lgam = (const float*)d_in[4];  // [1]

  float* outp   = (float*)d_out;                       // [16][2048][512]
  float* states = outp + (long)16 * 2048 * 512;        // [16][2049][512]
  float* ws = (float*)d_ws;

  const int NSQ = 8;
  float* sc = ws;                 // 3 scalars
  float* P  = ws + 64;            // (NSQ+1)*256 frobenius partials
  float* base = ws + 3456;

  // ws: squaring-chain buffers (dead after scalar_k), then overlaid
  float* Krt = base;                  // 1024^2
  float* Ma  = base + 1048576;        // 1024^2
  float* Mb  = base + 2097152;        // 1024^2  -> ends base+3145728
  float* K11t = base + 1048576;       // overlay Ma (after scalar_k)
  float* K12t = base + 1310720;
  float* ABst = base + 1572864;       // At f32
  _Float16* CtDtH  = (_Float16*)(ws + 3149248);   // [512][1024]
  _Float16* zerosH = (_Float16*)(ws + 3411392);   // [512][64] zeros

  // outp region (dead before final GEMM writes)
  float* Za  = outp;                  // [16][512][512] KS ping
  float* Zb  = outp + 4194304;        // [16][512][512] KS pong
  float* APb = outp + 8388608;        // At^j f32, j=2..8
  float* Tb  = outp + 10223616;       // Q^(2^k) f32, k=1..8
  _Float16* h16   = (_Float16*)(outp + 12320768);
  _Float16* ABstH = h16;                       // [512][1024]: AtH | BtH
  _Float16* APH_  = h16 + 524288;              // j=2..8
  _Float16* TmH_  = h16 + 2359296;             // k=1..8
  _Float16* XaH   = h16 + 4456448;
  _Float16* XbH   = XaH + 262144;
  _Float16* YnH   = XbH + 262144;
  _Float16* WH    = YnH + 262144;
  _Float16* K21tH = WH + 262144;
  _Float16* KrH   = K21tH + 262144;            // [1024][1024] -> ends h16+6815744
  float* St = outp + 15728640;                 // f32 Newton buffers in outp tail
  float* Xa = outp + 15990784;
  float* Xb = outp + 16252928;
  float* Yn = outp + 16515072;                 // ends 16777216 exactly

  auto APf = [&](int j) -> float* {
    return (j == 1) ? ABst : APb + (long)(j - 2) * 262144;
  };
  auto APH = [&](int j) -> _Float16* {
    return (j == 1) ? ABstH : APH_ + (long)(j - 2) * 262144;
  };
  auto APHld = [&](int j) { return (j == 1) ? 1024 : 512; };
  auto Tmf = [&](int k) -> float* { return (k == 0) ? APf(8) : Tb + (long)(k - 1) * 262144; };
  auto TmH = [&](int k) -> _Float16* { return (k == 0) ? APH(8) : TmH_ + (long)(k - 1) * 262144; };

  auto launch64 = [&](const GP* gs, int nb) {
    GPB pb; memset(&pb, 0, sizeof(pb));
    int mx = 0;
    for (int i = 0; i < nb; ++i) {
      pb.g[i] = gs[i];
      int b = ((gs[i].M + 63) / 64) * ((gs[i].N + 63) / 64);
      if (b > mx) mx = b;
    }
    gemm_u64<<<dim3(mx, nb), dim3(256), 0, stream>>>(pb);
  };
  auto launch128 = [&](const GP* gs, int nb) {
    GPB pb; memset(&pb, 0, sizeof(pb));
    int mx = 0;
    for (int i = 0; i < nb; ++i) {
      pb.g[i] = gs[i];
      int b = ((gs[i].M + 127) / 128) * ((gs[i].N + 127) / 128);
      if (b > mx) mx = b;
    }
    gemm_u128<<<dim3(mx, nb), dim3(256), 0, stream>>>(pb);
  };

  // mode-2 512^3 helper: C f32 (optional) + f16 transposed shadow
  auto mmh = [&](const float* A, const _Float16* Bh, int ldbh,
                 float* C, _Float16* Ch, int ldh) {
    GP g = gp0(); g.M = 512; g.N = 512; g.K1 = 512;
    g.A1 = A; g.a1 = lin(512);
    g.Bh = Bh; g.ldbh = ldbh;
    g.C1 = C; g.c1 = lin(512);
    g.C1h = Ch; g.ldh = ldh;
    return g;
  };
  // zero-B copy GP: C1 = E1 (K=64 against a zero f16 block)
  auto cpGP = [&](const float* src, Addr sa, float* dst, Addr da, int M) {
    GP g = gp0(); g.M = M; g.N = 512; g.K1 = 64;
    g.A1 = src; g.a1 = sa;
    g.Bh = zerosH; g.ldbh = 64;
    g.E1 = src; g.e1 = sa; g.beta = 1.0f;
    g.C1 = dst; g.c1 = da;
    return g;
  };

  hipMemsetAsync(zerosH, 0, 512 * 64 * sizeof(_Float16), stream);

  // ---- phase 0: transposes needed by squaring chain + Newton ----
  tr_k<<<dim3(1024), dim3(32, 8), 0, stream>>>(Kr, 1024, 0, 0, Krt, 1024,
                                               nullptr, 1.f, 0.f, 1.f);     // Kr^T
  trh_k<<<dim3(1024), dim3(32, 8), 0, stream>>>(Kr, 1024, KrH);
  tr_k<<<dim3(256), dim3(32, 8), 0, stream>>>(S, 512, 0, 0, St, 512,
                                              nullptr, 1.f, 0.f, 1.f);      // St = S^T
  tr_k<<<dim3(256), dim3(32, 8), 0, stream>>>(S, 512, 0, 0, Xa, 512,
                                              nullptr, 1.f, 2.f, -1.f);     // X0 = 2I - S^T
  sc_k<<<dim3(1024), dim3(256), 0, stream>>>(S, 512, 0, 0, XaH, 512,
                                             nullptr, -1.f, 2.f);           // X0H = 2I - S
  // Za slot 0 = initial state (read only by KS round 0)
  copy_rows_k<<<dim3(8), dim3(256), 0, stream>>>(st0, lin(512), Za, lin(262144),
                                                 16, 128);

  // ---- phase A: squaring chain (9 dispatches) with Newton piggyback ----
  {
    // d1: M0 = Kr^T @ Kr  +  Newton1a: Yn = St @ X0
    GP gs[2];
    gs[0] = gp0();
    gs[0].M = 1024; gs[0].N = 1024; gs[0].K1 = 1024;
    gs[0].A1 = Krt; gs[0].a1 = lin(1024);
    gs[0].Bh = KrH; gs[0].ldbh = 1024;
    gs[0].C1 = Ma; gs[0].c1 = lin(1024);
    gs[0].fout = P;
    gs[1] = mmh(St, XaH, 512, Yn, YnH, 512);
    launch64(gs, 2);
  }
  for (int k = 1; k <= NSQ; ++k) {
    float* cur = (k % 2 == 1) ? Ma : Mb;
    float* nxt = (k % 2 == 1) ? Mb : Ma;
    GP gs[2];
    gs[0] = gp0();
    gs[0].M = 1024; gs[0].N = 1024; gs[0].K1 = 1024;
    gs[0].A1 = cur; gs[0].a1 = lin(1024);
    gs[0].B = cur; gs[0].ldb = 1024;          // mode-1 (symmetric)
    gs[0].C1 = nxt; gs[0].c1 = lin(1024);
    gs[0].fin = P + (long)(k - 1) * 256;
    gs[0].fout = P + (long)k * 256;
    int nb = 1;
    if (k <= 6) {
      // Newton steps 1b..3b on squarings 1..6
      if (k % 2 == 1) { // 'b' step of iter (k+1)/2: X' = 2X - X@Yn
        float* cx = (k == 1 || k == 5) ? Xa : Xb;
        float* nx = (k == 1 || k == 5) ? Xb : Xa;
        _Float16* nxH = (k == 1 || k == 5) ? XbH : XaH;
        GP h = mmh(cx, YnH, 512, nx, nxH, 512);
        h.alpha = -1.0f; h.E1 = cx; h.e1 = lin(512); h.beta = 2.0f;
        gs[1] = h; nb = 2;
      } else {          // 'a' step: Yn = St @ X
        _Float16* cxH = (k == 2) ? XbH : XaH;
        gs[1] = mmh(St, cxH, 512, Yn, YnH, 512); nb = 2;
      }
    }
    launch64(gs, nb);
  }
  // SinvT = Xb / XbH (3 Newton iterations complete)
  scalar_k<<<1, 256, 0, stream>>>(P, NSQ, lgam, sc);

  // ---- phase B: sigma-scaled operands ----
  tr_k<<<dim3(256), dim3(32, 8), 0, stream>>>(Kr, 1024, 0, 0, K11t, 512,
                                              sc, 1.f, 0.f, 1.f);           // K11^T*invk
  tr_k<<<dim3(256), dim3(32, 8), 0, stream>>>(Kr, 1024, 0, 512, K12t, 512,
                                              sc, 1.f, 0.f, 1.f);           // K12^T*invk
  sc_k<<<dim3(1024), dim3(256), 0, stream>>>(Kr, 1024, 512, 0, K21tH, 512,
                                             sc, 1.f, 0.f);                 // invk*K21
  sc_k<<<dim3(1024), dim3(256), 0, stream>>>(Kr, 1024, 512, 512, CtDtH + 512, 1024,
                                             sc + 2, 1.f, 0.f);             // DtH
  {
    GP gs[2];
    gs[0] = mmh(K11t, XbH, 512, nullptr, WH, 512);        // W = K11t @ SinvT
    gs[1] = mmh(St, K21tH, 512, nullptr, CtDtH, 1024);    // CtH
    launch64(gs, 2);
  }
  {
    GP gs[2];
    gs[0] = mmh(St, WH, 512, ABst, ABstH, 1024);          // At (+AtH)
    gs[1] = mmh(K12t, XbH, 512, nullptr, ABstH + 512, 1024); // BtH = gamma*...
    gs[1].scale = sc + 1;
    launch64(gs, 2);
  }
  { GP g = mmh(APf(1), APH(1), 1024, APf(2), APH(2), 512); launch64(&g, 1); }
  { GP gs[2] = { mmh(APf(2), APH(1), 1024, APf(3), APH(3), 512),
                 mmh(APf(2), APH(2), 512,  APf(4), APH(4), 512) };
    launch64(gs, 2); }
  { GP gs[4];
    for (int i = 1; i <= 4; ++i)
      gs[i - 1] = mmh(APf(4), APH(i), APHld(i), APf(4 + i), APH(4 + i), 512);
    launch64(gs, 4); }

  // Addressing constants (L=8, 256 chunks/batch)
  const Addr A_u8   = two(8, 1048576, 255, 4096);
  const Addr A_s8   = two(8, 1049088, 255, 4096);
  const Addr A_z    = two(8, 262144, 255, 512);
  const Addr A_srow = two(11, 1049088, 2047, 512);

  // ---- phase C: pass1 (8 steps) with T-chain piggyback ----
  for (int j = 1; j <= 8; ++j) {
    GP gs[2];
    gs[0] = gp0();
    gs[0].M = 4096; gs[0].N = 512;
    if (j == 1) {
      gs[0].K1 = 512; gs[0].A1 = u; gs[0].a1 = A_u8;
      gs[0].Bh = ABstH + 512; gs[0].ldbh = 1024;   // Bt only
    } else {
      gs[0].K1 = 512; gs[0].A1 = states + (long)(j - 1) * 512; gs[0].a1 = A_s8;
      gs[0].K2 = 512; gs[0].A2 = u + (long)(j - 1) * 512; gs[0].a2 = A_u8;
      gs[0].Bh = ABstH; gs[0].ldbh = 1024;         // [At; Bt]
    }
    if (j == 8) { gs[0].C1 = Za + 512; gs[0].c1 = A_z; }
    else { gs[0].C1 = states + (long)j * 512; gs[0].c1 = A_s8; }
    gs[1] = mmh(Tmf(j - 1), TmH(j - 1), 512, Tmf(j), TmH(j), 512);  // T-chain
    launch64(gs, 2);
  }

  // ---- phase E: Kogge-Stone over 257 chunk states (copy folded in) ----
  for (int k = 0; k <= 8; ++k) {
    const int s = 1 << k;
    float* Zs = (k % 2 == 0) ? Za : Zb;
    float* Zd = (k % 2 == 0) ? Zb : Za;
    GP gs[2];
    gs[0] = gp0();
    gs[0].M = 4096; gs[0].N = 512; gs[0].K1 = 512;
    gs[0].A1 = Zs; gs[0].a1 = A_z;
    gs[0].Bh = TmH(k); gs[0].ldbh = 512;
    gs[0].E1 = Zs + (long)s * 512; gs[0].e1 = A_z; gs[0].beta = 1.0f;
    gs[0].C1 = Zd + (long)s * 512; gs[0].c1 = A_z;
    const Addr lowA = two(k, 262144, s - 1, 512);
    gs[1] = cpGP(Zs, lowA, Zd, lowA, 16 * s);    // carry slots c<s
    launch64(gs, 2);
  }
  float* Zf = Zb;

  // ---- phase F: corrections + states-extreme copies (one dispatch) ----
  {
    GP gs[9];
    for (int j = 1; j <= 7; ++j) {
      GP g = gp0();
      g.M = 4096; g.N = 512; g.K1 = 512;
      g.A1 = Zf; g.a1 = A_z;
      g.Bh = APH(j); g.ldbh = APHld(j);
      g.C2 = states + (long)j * 512; g.c2 = A_s8;
      g.E2 = states + (long)j * 512; g.e2 = A_s8;
      gs[j - 1] = g;
    }
    gs[7] = cpGP(Zf, A_z, states, A_s8, 4096);                     // states[c*8]
    gs[8] = cpGP(Zf + (long)256 * 512, lin(262144),
                 states + (long)2048 * 512, lin(1049088), 16);     // states[2048]
    launch128(gs, 9);
  }

  // ---- output = states[:, :T] @ Ct + u @ Dt ----
  {
    GP g = gp0();
    g.M = 32768; g.N = 512;
    g.K1 = 512; g.A1 = states; g.a1 = A_srow;
    g.K2 = 512; g.A2 = u; g.a2 = lin(512);
    g.Bh = CtDtH; g.ldbh = 1024;
    g.C1 = outp; g.c1 = lin(512);
    launch128(&g, 1);
  }
}